// Round 7
// baseline (717.168 us; speedup 1.0000x reference)
//
#include <hip/hip_runtime.h>
#include <hip/hip_bf16.h>

typedef __attribute__((ext_vector_type(8))) _Float16 half8;
typedef __attribute__((ext_vector_type(4))) _Float16 half4v;
typedef __attribute__((ext_vector_type(4))) float f32x4;

__device__ __forceinline__ float wred_max(float v){
  #pragma unroll
  for (int o = 32; o; o >>= 1) v = fmaxf(v, __shfl_xor(v, o));
  return v;
}
__device__ __forceinline__ float wred_sum(float v){
  #pragma unroll
  for (int o = 32; o; o >>= 1) v += __shfl_xor(v, o);
  return v;
}
__device__ __forceinline__ unsigned f2k(float f){
  unsigned u = __float_as_uint(f);
  return (u & 0x80000000u) ? ~u : (u | 0x80000000u);
}

#define GLOAD16(GP, LP) __builtin_amdgcn_global_load_lds( \
    (const __attribute__((address_space(1))) void*)(GP),  \
    (__attribute__((address_space(3))) void*)(LP), 16, 0, 0)

// ======== MFMA GEMM (f16 in, f32 acc): C = alpha * A(MxK) @ B(NxK)^T (+bias) ========
template<int BM, int BN, int OUT_F16, int ACT>
__global__ __launch_bounds__(256) void gemm_ht(
    const _Float16* __restrict__ A, long saz, int lda,
    const _Float16* __restrict__ B, long sbz, int ldb,
    void* __restrict__ Cv, long scz, int ldc,
    int K, float alpha, const float* __restrict__ bias)
{
  constexpr int FM = BM / 32, FN = BN / 32;
  __shared__ __align__(16) _Float16 Asl[BM * 32];
  __shared__ __align__(16) _Float16 Bsl[BN * 32];
  const int t = threadIdx.x;
  const int wid = t >> 6, lane = t & 63;
  const int wr = wid >> 1, wc = wid & 1;
  const int lr = lane & 15, kg = lane >> 4;
  A += (long)blockIdx.z * saz;
  B += (long)blockIdx.z * sbz;
  const long row0 = (long)blockIdx.y * BM;
  const long col0 = (long)blockIdx.x * BN;

  f32x4 acc[FM][FN];
  #pragma unroll
  for (int i = 0; i < FM; i++)
    #pragma unroll
    for (int j = 0; j < FN; j++)
      acc[i][j] = (f32x4){0.f, 0.f, 0.f, 0.f};

  const int arow_t = t >> 2, acol_t = (t & 3) * 8;

  for (int k0 = 0; k0 < K; k0 += 32){
    #pragma unroll
    for (int r = 0; r < BM / 64; r++){
      const _Float16* gp = A + (row0 + r*64 + arow_t) * (long)lda + k0 + acol_t;
      GLOAD16(gp, (char*)Asl + r*4096 + wid*1024);
    }
    #pragma unroll
    for (int r = 0; r < BN / 64; r++){
      const _Float16* gp = B + (col0 + r*64 + arow_t) * (long)ldb + k0 + acol_t;
      GLOAD16(gp, (char*)Bsl + r*4096 + wid*1024);
    }
    __syncthreads();
    half8 af[FM], bfv[FN];
    #pragma unroll
    for (int i = 0; i < FM; i++)
      af[i] = *(const half8*)((const char*)Asl + (wr*(BM/2) + i*16 + lr)*64 + kg*16);
    #pragma unroll
    for (int j = 0; j < FN; j++)
      bfv[j] = *(const half8*)((const char*)Bsl + (wc*(BN/2) + j*16 + lr)*64 + kg*16);
    #pragma unroll
    for (int i = 0; i < FM; i++)
      #pragma unroll
      for (int j = 0; j < FN; j++)
        acc[i][j] = __builtin_amdgcn_mfma_f32_16x16x32_f16(af[i], bfv[j], acc[i][j], 0, 0, 0);
    __syncthreads();
  }

  _Float16* Ch = (_Float16*)Cv + (long)blockIdx.z * scz;
  float*    Cf = (float*)Cv    + (long)blockIdx.z * scz;
  #pragma unroll
  for (int i = 0; i < FM; i++){
    #pragma unroll
    for (int j = 0; j < FN; j++){
      #pragma unroll
      for (int q = 0; q < 4; q++){
        long rr = row0 + wr*(BM/2) + i*16 + kg*4 + q;
        long cc = col0 + wc*(BN/2) + j*16 + lr;
        float val = acc[i][j][q] * alpha;
        if (bias) val += bias[cc];
        if constexpr (ACT) val = 0.5f * val * (1.0f + erff(val * 0.70710678118654752f));
        if constexpr (OUT_F16) Ch[rr*(long)ldc + cc] = (_Float16)val;
        else                   Cf[rr*(long)ldc + cc] = val;
      }
    }
  }
}

// ======== fused flash local attention: O = softmax(Q K^T * scale) V ========
// QBLK=64, KT=64, D=256. grid = 128 (XCD-affinity mapping). 4 waves (2x2).
__global__ __launch_bounds__(256) void flash_local(
    const _Float16* __restrict__ Qb,   // qkv_l + 0   (row stride 768)
    const _Float16* __restrict__ Kb,   // qkv_l + 256 (row stride 768)
    const _Float16* __restrict__ Vt,   // [2][256][4096]
    _Float16* __restrict__ comb,       // [8192][1024], writes cols 0:256
    float scale)
{
  __shared__ __align__(16) _Float16 Kl[64*256];   // 32KB; row=512B=32 chunks
  __shared__ __align__(16) _Float16 Vl[256*64];   // 32KB; row=128B=8 chunks
  __shared__ __align__(16) _Float16 Pl[64*64];    // 8KB;  row=128B=8 chunks
  __shared__ float rmax[2][64];
  __shared__ float rsum[2][64];

  const int t = threadIdx.x, wid = t >> 6, lane = t & 63;
  const int wr = wid >> 1, wc = wid & 1;
  const int g = lane >> 4, lr = lane & 15;

  // XCD-affinity: batch b on XCDs [4b,4b+4) so each XCD's K+V working set = 4MB (L2-size)
  const int bid = blockIdx.x;
  const int xcd = bid & 7;
  const int batch = xcd >> 2;
  const int qb = (xcd & 3) * 16 + (bid >> 3);     // 0..63
  const long QZe = (long)4096 * 768;
  const _Float16* Q = Qb + (long)batch * QZe;
  const _Float16* K = Kb + (long)batch * QZe;
  const _Float16* V = Vt + (long)batch * ((long)256 * 4096);
  const int q0 = qb * 64;

  // Q fragments in regs: rows wr*32 + i*16 + lr, k = ks*32 + g*8
  half8 qf[2][8];
  #pragma unroll
  for (int i = 0; i < 2; i++){
    const _Float16* qp = Q + (long)(q0 + wr*32 + i*16 + lr) * 768 + g*8;
    #pragma unroll
    for (int ks = 0; ks < 8; ks++)
      qf[i][ks] = *(const half8*)(qp + ks*32);
  }

  float m_run[2][4], l_run[2][4];
  f32x4 acco[2][8];
  #pragma unroll
  for (int i = 0; i < 2; i++)
    #pragma unroll
    for (int q = 0; q < 4; q++){ m_run[i][q] = -3.0e38f; l_run[i][q] = 0.f; }
  #pragma unroll
  for (int i = 0; i < 2; i++)
    #pragma unroll
    for (int f = 0; f < 8; f++)
      acco[i][f] = (f32x4){0.f, 0.f, 0.f, 0.f};

  for (int kt = 0; kt < 64; kt++){
    const int kv0 = kt * 64;
    // ---- stage K tile [64][256] with XOR-swizzled source chunks ----
    #pragma unroll
    for (int i = 0; i < 8; i++){
      int L = i*256 + t;
      int r = L >> 5, c = L & 31;
      const _Float16* gp = K + (long)(kv0 + r)*768 + ((c ^ (r & 7)) * 8);
      GLOAD16(gp, (char*)Kl + (i*256 + wid*64)*16);
    }
    // ---- stage V^T tile [256][64] ----
    #pragma unroll
    for (int i = 0; i < 8; i++){
      int L = i*256 + t;
      int d = L >> 3, c = L & 7;
      const _Float16* gp = V + (long)d*4096 + kv0 + ((c ^ (d & 7)) * 8);
      GLOAD16(gp, (char*)Vl + (i*256 + wid*64)*16);
    }
    __syncthreads();

    // ---- S = Q K^T (16x16x32 MFMA), per wave 16x32 of the 64x64 tile x2 rows ----
    f32x4 accs[2][2];
    #pragma unroll
    for (int i = 0; i < 2; i++)
      #pragma unroll
      for (int j = 0; j < 2; j++)
        accs[i][j] = (f32x4){0.f, 0.f, 0.f, 0.f};
    #pragma unroll
    for (int ks = 0; ks < 8; ks++){
      #pragma unroll
      for (int j = 0; j < 2; j++){
        int n = wc*32 + j*16 + lr;
        int c = (ks*4 + g) ^ (n & 7);
        half8 kf = *(const half8*)((const char*)Kl + n*512 + c*16);
        accs[0][j] = __builtin_amdgcn_mfma_f32_16x16x32_f16(qf[0][ks], kf, accs[0][j], 0, 0, 0);
        accs[1][j] = __builtin_amdgcn_mfma_f32_16x16x32_f16(qf[1][ks], kf, accs[1][j], 0, 0, 0);
      }
    }
    #pragma unroll
    for (int i = 0; i < 2; i++)
      #pragma unroll
      for (int j = 0; j < 2; j++)
        #pragma unroll
        for (int q = 0; q < 4; q++)
          accs[i][j][q] *= scale;

    // ---- per-row tile max (reduce over 16 lanes sharing g, then across wc via LDS) ----
    float tmax[2][4];
    #pragma unroll
    for (int i = 0; i < 2; i++)
      #pragma unroll
      for (int q = 0; q < 4; q++)
        tmax[i][q] = fmaxf(accs[i][0][q], accs[i][1][q]);
    #pragma unroll
    for (int o = 1; o < 16; o <<= 1)
      #pragma unroll
      for (int i = 0; i < 2; i++)
        #pragma unroll
        for (int q = 0; q < 4; q++)
          tmax[i][q] = fmaxf(tmax[i][q], __shfl_xor(tmax[i][q], o));
    if (lr == 0){
      #pragma unroll
      for (int i = 0; i < 2; i++)
        #pragma unroll
        for (int q = 0; q < 4; q++)
          rmax[wc][wr*32 + i*16 + g*4 + q] = tmax[i][q];
    }
    __syncthreads();

    // ---- online update: m_new, alpha; P = exp(S - m_new); partial rowsums ----
    float alpha[2][4], tsum[2][4];
    #pragma unroll
    for (int i = 0; i < 2; i++)
      #pragma unroll
      for (int q = 0; q < 4; q++){
        int row = wr*32 + i*16 + g*4 + q;
        float tm = fmaxf(rmax[0][row], rmax[1][row]);
        float mn = fmaxf(m_run[i][q], tm);
        alpha[i][q] = expf(m_run[i][q] - mn);
        m_run[i][q] = mn;
      }
    #pragma unroll
    for (int i = 0; i < 2; i++)
      #pragma unroll
      for (int j = 0; j < 2; j++)
        #pragma unroll
        for (int q = 0; q < 4; q++)
          accs[i][j][q] = expf(accs[i][j][q] - m_run[i][q]);
    #pragma unroll
    for (int i = 0; i < 2; i++)
      #pragma unroll
      for (int q = 0; q < 4; q++)
        tsum[i][q] = accs[i][0][q] + accs[i][1][q];
    #pragma unroll
    for (int o = 1; o < 16; o <<= 1)
      #pragma unroll
      for (int i = 0; i < 2; i++)
        #pragma unroll
        for (int q = 0; q < 4; q++)
          tsum[i][q] += __shfl_xor(tsum[i][q], o);
    if (lr == 0){
      #pragma unroll
      for (int i = 0; i < 2; i++)
        #pragma unroll
        for (int q = 0; q < 4; q++)
          rsum[wc][wr*32 + i*16 + g*4 + q] = tsum[i][q];
    }
    // ---- write P (f16) into swizzled LDS tile ----
    #pragma unroll
    for (int i = 0; i < 2; i++)
      #pragma unroll
      for (int j = 0; j < 2; j++)
        #pragma unroll
        for (int q = 0; q < 4; q++){
          int row = wr*32 + i*16 + g*4 + q;
          int col = wc*32 + j*16 + lr;
          int cb = col * 2;
          int byte = row*128 + (((cb >> 4) ^ (row & 7)) << 4) + (cb & 15);
          *(_Float16*)((char*)Pl + byte) = (_Float16)accs[i][j][q];
        }
    __syncthreads();

    // ---- l update + O rescale ----
    #pragma unroll
    for (int i = 0; i < 2; i++)
      #pragma unroll
      for (int q = 0; q < 4; q++){
        int row = wr*32 + i*16 + g*4 + q;
        l_run[i][q] = l_run[i][q]*alpha[i][q] + (rsum[0][row] + rsum[1][row]);
      }
    #pragma unroll
    for (int i = 0; i < 2; i++)
      #pragma unroll
      for (int f = 0; f < 8; f++)
        #pragma unroll
        for (int q = 0; q < 4; q++)
          acco[i][f][q] *= alpha[i][q];

    // ---- O += P V : per wave 32x128, A=P(LDS), B=Vt tile(LDS) ----
    #pragma unroll
    for (int kk = 0; kk < 2; kk++){
      half8 pa[2];
      #pragma unroll
      for (int i = 0; i < 2; i++){
        int rA = wr*32 + i*16 + lr;
        int c = (kk*4 + g) ^ (rA & 7);
        pa[i] = *(const half8*)((const char*)Pl + rA*128 + c*16);
      }
      #pragma unroll
      for (int f = 0; f < 8; f++){
        int d = wc*128 + f*16 + lr;
        int c = (kk*4 + g) ^ (d & 7);
        half8 vb = *(const half8*)((const char*)Vl + d*128 + c*16);
        acco[0][f] = __builtin_amdgcn_mfma_f32_16x16x32_f16(pa[0], vb, acco[0][f], 0, 0, 0);
        acco[1][f] = __builtin_amdgcn_mfma_f32_16x16x32_f16(pa[1], vb, acco[1][f], 0, 0, 0);
      }
    }
    __syncthreads();
  }

  // ---- epilogue: O/l -> comb cols 0:256 ----
  #pragma unroll
  for (int i = 0; i < 2; i++)
    #pragma unroll
    for (int f = 0; f < 8; f++)
      #pragma unroll
      for (int q = 0; q < 4; q++){
        long row = (long)batch*4096 + q0 + wr*32 + i*16 + g*4 + q;
        int col = wc*128 + f*16 + lr;
        comb[row*1024 + col] = (_Float16)(acco[i][f][q] / l_run[i][q]);
      }
}

// ======== split-K PV GEMM, BN=256 full width: f32 partials ========
template<int BM, int BN>
__global__ __launch_bounds__(256) void gemm_pv(
    const _Float16* __restrict__ A, long saz, int lda,
    const _Float16* __restrict__ B, long sbz, int ldb,
    float* __restrict__ P, int nsplit, int Ksplit)
{
  constexpr int FM = BM / 32, FN = BN / 32;
  __shared__ __align__(16) _Float16 Asl[BM * 32];
  __shared__ __align__(16) _Float16 Bsl[BN * 32];
  const int t = threadIdx.x;
  const int wid = t >> 6, lane = t & 63;
  const int wr = wid >> 1, wc = wid & 1;
  const int lr = lane & 15, kg = lane >> 4;
  const int z = blockIdx.z, batch = z / nsplit, split = z % nsplit;
  A += (long)batch * saz;
  B += (long)batch * sbz;
  float* Pz = P + (size_t)z * (4096 * 256);
  const long row0 = (long)blockIdx.y * BM;
  const int Kbase = split * Ksplit;

  f32x4 acc[FM][FN];
  #pragma unroll
  for (int i = 0; i < FM; i++)
    #pragma unroll
    for (int j = 0; j < FN; j++)
      acc[i][j] = (f32x4){0.f, 0.f, 0.f, 0.f};

  const int arow_t = t >> 2, acol_t = (t & 3) * 8;

  for (int k0 = 0; k0 < Ksplit; k0 += 32){
    #pragma unroll
    for (int r = 0; r < BM / 64; r++){
      const _Float16* gp = A + (row0 + r*64 + arow_t) * (long)lda + Kbase + k0 + acol_t;
      GLOAD16(gp, (char*)Asl + r*4096 + wid*1024);
    }
    #pragma unroll
    for (int r = 0; r < BN / 64; r++){
      const _Float16* gp = B + (r*64 + arow_t) * (long)ldb + Kbase + k0 + acol_t;
      GLOAD16(gp, (char*)Bsl + r*4096 + wid*1024);
    }
    __syncthreads();
    half8 af[FM], bfv[FN];
    #pragma unroll
    for (int i = 0; i < FM; i++)
      af[i] = *(const half8*)((const char*)Asl + (wr*(BM/2) + i*16 + lr)*64 + kg*16);
    #pragma unroll
    for (int j = 0; j < FN; j++)
      bfv[j] = *(const half8*)((const char*)Bsl + (wc*(BN/2) + j*16 + lr)*64 + kg*16);
    #pragma unroll
    for (int i = 0; i < FM; i++)
      #pragma unroll
      for (int j = 0; j < FN; j++)
        acc[i][j] = __builtin_amdgcn_mfma_f32_16x16x32_f16(af[i], bfv[j], acc[i][j], 0, 0, 0);
    __syncthreads();
  }

  #pragma unroll
  for (int i = 0; i < FM; i++)
    #pragma unroll
    for (int j = 0; j < FN; j++)
      #pragma unroll
      for (int q = 0; q < 4; q++){
        long rr = row0 + wr*(BM/2) + i*16 + kg*4 + q;
        long cc = wc*(BN/2) + j*16 + lr;
        Pz[rr*256 + cc] = acc[i][j][q];
      }
}

// ======== sum 4 split-K partials -> f16 into comb at column offset ========
__global__ __launch_bounds__(256) void reduce4(const float* __restrict__ P,
                                               _Float16* __restrict__ dst, int coff, int nq){
  int i = blockIdx.x * 256 + threadIdx.x;
  if (i >= nq) return;
  int b = i >> 18;
  int r = i & 262143;
  int row = r >> 6, col4 = r & 63;
  const float4* P4 = (const float4*)P;
  float4 s = P4[(size_t)(b*4 + 0) * 262144 + r];
  #pragma unroll
  for (int sp = 1; sp < 4; sp++){
    float4 q = P4[(size_t)(b*4 + sp) * 262144 + r];
    s.x += q.x; s.y += q.y; s.z += q.z; s.w += q.w;
  }
  half4v o;
  o[0] = (_Float16)s.x; o[1] = (_Float16)s.y; o[2] = (_Float16)s.z; o[3] = (_Float16)s.w;
  *(half4v*)(dst + ((size_t)b*4096 + row)*1024 + coff + col4*4) = o;
}

// ======== cast f32 -> f16 (8 elems/thread) ========
__global__ __launch_bounds__(256) void cast_xh(const float* __restrict__ in,
                                               _Float16* __restrict__ out, int n8){
  int i = blockIdx.x * 256 + threadIdx.x;
  const int stride = gridDim.x * 256;
  for (; i < n8; i += stride){
    float4 a = ((const float4*)in)[2*i];
    float4 b = ((const float4*)in)[2*i + 1];
    half8 o;
    o[0]=(_Float16)a.x; o[1]=(_Float16)a.y; o[2]=(_Float16)a.z; o[3]=(_Float16)a.w;
    o[4]=(_Float16)b.x; o[5]=(_Float16)b.y; o[6]=(_Float16)b.z; o[7]=(_Float16)b.w;
    *(half8*)(out + (size_t)i*8) = o;
  }
}

// ======== transpose+cast weight: in (R x C) f32 -> out (C x R) f16 ========
__global__ __launch_bounds__(256) void transpose_cast_w(const float* __restrict__ in, int R, int C,
                                                        _Float16* __restrict__ out){
  __shared__ float tile[32][33];
  const int c0 = blockIdx.x * 32, r0 = blockIdx.y * 32;
  const int tx = threadIdx.x & 31, ty = threadIdx.x >> 5;
  #pragma unroll
  for (int i = 0; i < 32; i += 8)
    tile[ty+i][tx] = in[(size_t)(r0+ty+i)*C + c0+tx];
  __syncthreads();
  #pragma unroll
  for (int i = 0; i < 32; i += 8)
    out[(size_t)(c0+ty+i)*R + r0+tx] = (_Float16)tile[tx][ty+i];
}

// ======== f16 transpose: in (R x C, ld_in) -> out (C x R, ld_out), z-batched ========
__global__ __launch_bounds__(256) void transpose_h(
    const _Float16* __restrict__ in, long in_z, int ld_in,
    _Float16* __restrict__ out, long out_z, int ld_out)
{
  __shared__ _Float16 tile[32][34];
  const _Float16* ip = in + (long)blockIdx.z * in_z;
  _Float16* op = out + (long)blockIdx.z * out_z;
  const int c0 = blockIdx.x * 32, r0 = blockIdx.y * 32;
  const int tx = threadIdx.x & 31, ty = threadIdx.x >> 5;
  #pragma unroll
  for (int i = 0; i < 32; i += 8)
    tile[ty+i][tx] = ip[(long)(r0+ty+i)*ld_in + c0+tx];
  __syncthreads();
  #pragma unroll
  for (int i = 0; i < 32; i += 8)
    op[(long)(c0+ty+i)*ld_out + r0+tx] = tile[tx][ty+i];
}

// ======== exact top-k (4x8-bit radix, per-wave hist + shfl scan) + masked softmax ========
__global__ __launch_bounds__(256) void sparse_softmax_inplace(float* __restrict__ sc, int ksel){
  __shared__ unsigned hist4[4][256];
  __shared__ unsigned hrev[256];
  __shared__ unsigned suf[257];
  __shared__ unsigned wtot[4];
  __shared__ int selb;
  __shared__ float red[4], red2[4];
  const int t = threadIdx.x, lane = t & 63, wid = t >> 6;
  float* p = sc + (size_t)blockIdx.x * 4096;
  float v[16]; unsigned kk[16];
  #pragma unroll
  for (int j = 0; j < 4; j++){
    float4 q = *(const float4*)(p + t*16 + j*4);
    v[4*j] = q.x; v[4*j+1] = q.y; v[4*j+2] = q.z; v[4*j+3] = q.w;
  }
  #pragma unroll
  for (int e = 0; e < 16; e++) kk[e] = f2k(v[e]);
  float m = v[0];
  #pragma unroll
  for (int e = 1; e < 16; e++) m = fmaxf(m, v[e]);
  m = wred_max(m);
  if (lane == 0) red[wid] = m;
  __syncthreads();
  m = fmaxf(fmaxf(red[0], red[1]), fmaxf(red[2], red[3]));

  unsigned prefix = 0;
  unsigned remaining = (unsigned)ksel;
  for (int pass = 0; pass < 4; ++pass){
    const int shift = 24 - 8*pass;
    ((uint4*)hist4)[t] = (uint4){0u,0u,0u,0u};
    __syncthreads();
    #pragma unroll
    for (int e = 0; e < 16; e++){
      unsigned k = kk[e];
      bool cand = (pass == 0) || ((k >> (shift + 8)) == prefix);
      if (cand) atomicAdd(&hist4[wid][(k >> shift) & 255u], 1u);
    }
    __syncthreads();
    unsigned h = hist4[0][t] + hist4[1][t] + hist4[2][t] + hist4[3][t];
    hrev[t] = h;
    __syncthreads();
    unsigned x = hrev[255 - t];
    #pragma unroll
    for (int o = 1; o < 64; o <<= 1){
      unsigned y = __shfl_up(x, o);
      if (lane >= o) x += y;
    }
    if (lane == 63) wtot[wid] = x;
    __syncthreads();
    #pragma unroll
    for (int w = 0; w < 4; w++) if (w < wid) x += wtot[w];
    suf[255 - t] = x;
    if (t == 0) suf[256] = 0u;
    __syncthreads();
    if (suf[t] >= remaining && suf[t+1] < remaining) selb = t;
    __syncthreads();
    const int b = selb;
    remaining -= suf[b+1];
    prefix = (prefix << 8) | (unsigned)b;
  }
  const unsigned Tkey = prefix;

  float ev[16];
  float s = 0.f;
  #pragma unroll
  for (int e = 0; e < 16; e++){
    ev[e] = (kk[e] >= Tkey) ? expf(v[e] - m) : 0.f;
    s += ev[e];
  }
  s = wred_sum(s);
  if (lane == 0) red2[wid] = s;
  __syncthreads();
  s = red2[0] + red2[1] + red2[2] + red2[3];
  const float inv = 1.0f / s;
  _Float16* ph = (_Float16*)p;
  half8 o0, o1;
  #pragma unroll
  for (int e = 0; e < 8; e++){
    o0[e] = (_Float16)(ev[e]   * inv);
    o1[e] = (_Float16)(ev[8+e] * inv);
  }
  *(half8*)(ph + t*16)     = o0;
  *(half8*)(ph + t*16 + 8) = o1;
}

// ======== memory-head softmax over 64 scores: one wave per row ========
__global__ __launch_bounds__(256) void msoftmax64(const float* __restrict__ mscore,
                                                  _Float16* __restrict__ mprob){
  const int t = threadIdx.x, lane = t & 63, wid = t >> 6;
  const size_t row = (size_t)blockIdx.x * 4 + wid;
  float v = mscore[row*64 + lane];
  float m = wred_max(v);
  float e = expf(v - m);
  float s = wred_sum(e);
  mprob[row*64 + lane] = (_Float16)(e / s);
}

extern "C" void kernel_launch(void* const* d_in, const int* in_sizes, int n_in,
                              void* d_out, int out_size, void* d_ws, size_t ws_size,
                              hipStream_t stream)
{
  const float* x             = (const float*)d_in[0];
  const float* local_qkv_w   = (const float*)d_in[1];
  const float* sparse_qkv_w  = (const float*)d_in[2];
  const float* memory_bank   = (const float*)d_in[3];
  const float* memory_proj_w = (const float*)d_in[4];
  const float* mem_out_w     = (const float*)d_in[5];
  const float* mem_out_b     = (const float*)d_in[6];
  const float* pred_in_w     = (const float*)d_in[7];
  const float* pred_in_b     = (const float*)d_in[8];
  const float* pred1_w       = (const float*)d_in[9];
  const float* pred1_b       = (const float*)d_in[10];
  const float* pred2_w       = (const float*)d_in[11];
  const float* pred2_b       = (const float*)d_in[12];
  const float* warboss_w     = (const float*)d_in[13];
  const float* warboss_b     = (const float*)d_in[14];
  float* out = (float*)d_out;

  char* wsb = (char*)d_ws;
  float*     scores_f = (float*)wsb;                   // sparse f32 scores (one batch)
  _Float16*  x_h      = (_Float16*)wsb;
  _Float16*  mem_cat  = (_Float16*)(wsb + 16777216);
  _Float16*  h_in     = (_Float16*)(wsb + 25165824);
  _Float16*  h1       = (_Float16*)(wsb + 29360128);
  float*     mscore   = (float*)(wsb + 37748736);
  _Float16*  mprob    = (_Float16*)(wsb + 39845888);
  _Float16*  qkv_l    = (_Float16*)(wsb + 67108864);   // [8192][768]
  _Float16*  qkv_s    = (_Float16*)(wsb + 79691776);   // [8192][768]
  _Float16*  Vt       = (_Float16*)(wsb + 92274688);   // [2][256][4096]
  _Float16*  comb     = (_Float16*)(wsb + 96468992);   // [8192][1024]
  _Float16*  lqkvT    = (_Float16*)(wsb + 113246208);  // [768][1024]
  _Float16*  sqkvT    = lqkvT  + 786432;
  _Float16*  mprojT   = sqkvT  + 786432;               // [256][1024]
  _Float16*  moutT    = mprojT + 262144;               // [256][512]
  _Float16*  pinT     = moutT  + 131072;               // [256][1024]
  _Float16*  p1T      = pinT   + 262144;               // [512][256]
  _Float16*  p2T      = p1T    + 131072;               // [256][512]
  _Float16*  wbT      = p2T    + 131072;               // [1024][1024]
  _Float16*  bank_h   = wbT    + 1048576;              // [64][256]
  _Float16*  bankT_h  = bank_h + 16384;                // [256][64]

  const dim3 blk(256);
  const float scale = 0.0625f;
  const long QZ  = (long)4096 * 768;
  const long VZ  = (long)256 * 4096;
  const long CZ  = (long)4096 * 1024;

  // ---- casts / weight transposes ----
  cast_xh<<<dim3(2048), blk, 0, stream>>>(x, x_h, 1048576);
  cast_xh<<<dim3(8), blk, 0, stream>>>(memory_bank, bank_h, 2048);
  transpose_cast_w<<<dim3(24,32), blk, 0, stream>>>(local_qkv_w,  1024,  768, lqkvT);
  transpose_cast_w<<<dim3(24,32), blk, 0, stream>>>(sparse_qkv_w, 1024,  768, sqkvT);
  transpose_cast_w<<<dim3( 8,32), blk, 0, stream>>>(memory_proj_w,1024,  256, mprojT);
  transpose_cast_w<<<dim3( 8,16), blk, 0, stream>>>(mem_out_w,     512,  256, moutT);
  transpose_cast_w<<<dim3( 8,32), blk, 0, stream>>>(pred_in_w,    1024,  256, pinT);
  transpose_cast_w<<<dim3(16, 8), blk, 0, stream>>>(pred1_w,       256,  512, p1T);
  transpose_cast_w<<<dim3( 8,16), blk, 0, stream>>>(pred2_w,       512,  256, p2T);
  transpose_cast_w<<<dim3(32,32), blk, 0, stream>>>(warboss_w,    1024, 1024, wbT);
  transpose_cast_w<<<dim3( 8, 2), blk, 0, stream>>>(memory_bank,    64,  256, bankT_h);

  // ---- QKV projections ----
  gemm_ht<128,128,1,0><<<dim3(6,64), blk, 0, stream>>>(x_h,0,1024, lqkvT,0,1024, qkv_l,0,768, 1024, 1.f, nullptr);
  gemm_ht<128,128,1,0><<<dim3(6,64), blk, 0, stream>>>(x_h,0,1024, sqkvT,0,1024, qkv_s,0,768, 1024, 1.f, nullptr);

  // ---- memory head (GEMM chain) -> comb[:, 512:768] ----
  gemm_ht<128,64,1,0><<<dim3(4,64), blk, 0, stream>>>(x_h,0,1024, mprojT,0,1024, mem_cat,0,512, 1024, 1.f, nullptr);
  gemm_ht<128,64,0,0><<<dim3(1,64), blk, 0, stream>>>(mem_cat,0,512, bank_h,0,256, (void*)mscore,0,64, 256, 1.f, nullptr);
  msoftmax64<<<dim3(2048), blk, 0, stream>>>(mscore, mprob);
  gemm_ht<128,64,1,0><<<dim3(4,64), blk, 0, stream>>>(mprob,0,64, bankT_h,0,64, mem_cat+256,0,512, 64, 1.f, nullptr);
  gemm_ht<128,64,1,0><<<dim3(4,64), blk, 0, stream>>>(mem_cat,0,512, moutT,0,512, comb+512,0,1024, 512, 1.f, mem_out_b);

  // ---- prediction head -> comb[:, 768:1024] ----
  gemm_ht<128,64,1,0><<<dim3(4,64), blk, 0, stream>>>(x_h,0,1024, pinT,0,1024, h_in,0,256, 1024, 1.f, pred_in_b);
  gemm_ht<128,128,1,1><<<dim3(4,64), blk, 0, stream>>>(h_in,0,256, p1T,0,256, h1,0,512, 256, 1.f, pred1_b);
  gemm_ht<128,64,1,0><<<dim3(4,64), blk, 0, stream>>>(h1,0,512, p2T,0,512, comb+768,0,1024, 512, 1.f, pred2_b);

  // ---- local (full) attention: fused flash -> comb[:, 0:256] ----
  transpose_h<<<dim3(8,128,2), blk, 0, stream>>>(qkv_l+512, QZ, 768, Vt, VZ, 4096);
  flash_local<<<dim3(128), blk, 0, stream>>>(qkv_l, qkv_l+256, Vt, comb, scale);

  // ---- sparse (top-k) attention -> comb[:, 256:512]; f32 scores per batch ----
  transpose_h<<<dim3(8,128,2), blk, 0, stream>>>(qkv_s+512, QZ, 768, Vt, VZ, 4096);
  for (int b = 0; b < 2; b++){
    const _Float16* Q = qkv_s + (long)b * QZ;
    gemm_ht<128,128,0,0><<<dim3(32,32), blk, 0, stream>>>(Q,0,768, Q+256,0,768, (void*)scores_f,0,4096, 256, scale, nullptr);
    sparse_softmax_inplace<<<dim3(4096), blk, 0, stream>>>(scores_f, 409);
    gemm_pv<64,256><<<dim3(1,64,4), blk, 0, stream>>>((const _Float16*)scores_f,0,8192, Vt + (long)b*VZ,0,4096, out, 4, 1024);
    reduce4<<<dim3(1024), blk, 0, stream>>>(out, comb + (long)b*CZ, 256, 262144);
  }

  // ---- output projection (f32 out) ----
  gemm_ht<128,128,0,0><<<dim3(8,64), blk, 0, stream>>>(comb,0,1024, wbT,0,1024, (void*)out,0,1024, 1024, 1.f, warboss_b);
}

// Round 8
// 603.840 us; speedup vs baseline: 1.1877x; 1.1877x over previous
//
#include <hip/hip_runtime.h>
#include <hip/hip_bf16.h>

typedef __attribute__((ext_vector_type(8))) _Float16 half8;
typedef __attribute__((ext_vector_type(4))) _Float16 half4v;
typedef __attribute__((ext_vector_type(4))) float f32x4;

__device__ __forceinline__ float wred_max(float v){
  #pragma unroll
  for (int o = 32; o; o >>= 1) v = fmaxf(v, __shfl_xor(v, o));
  return v;
}
__device__ __forceinline__ float wred_sum(float v){
  #pragma unroll
  for (int o = 32; o; o >>= 1) v += __shfl_xor(v, o);
  return v;
}
__device__ __forceinline__ unsigned f2k(float f){
  unsigned u = __float_as_uint(f);
  return (u & 0x80000000u) ? ~u : (u | 0x80000000u);
}

#define GLOAD16(GP, LP) __builtin_amdgcn_global_load_lds( \
    (const __attribute__((address_space(1))) void*)(GP),  \
    (__attribute__((address_space(3))) void*)(LP), 16, 0, 0)

// ======== MFMA GEMM (f16 in, f32 acc): C = alpha * A(MxK) @ B(NxK)^T (+bias) ========
template<int BM, int BN, int OUT_F16, int ACT>
__global__ __launch_bounds__(256) void gemm_ht(
    const _Float16* __restrict__ A, long saz, int lda,
    const _Float16* __restrict__ B, long sbz, int ldb,
    void* __restrict__ Cv, long scz, int ldc,
    int K, float alpha, const float* __restrict__ bias)
{
  constexpr int FM = BM / 32, FN = BN / 32;
  __shared__ __align__(16) _Float16 Asl[BM * 32];
  __shared__ __align__(16) _Float16 Bsl[BN * 32];
  const int t = threadIdx.x;
  const int wid = t >> 6, lane = t & 63;
  const int wr = wid >> 1, wc = wid & 1;
  const int lr = lane & 15, kg = lane >> 4;
  A += (long)blockIdx.z * saz;
  B += (long)blockIdx.z * sbz;
  const long row0 = (long)blockIdx.y * BM;
  const long col0 = (long)blockIdx.x * BN;

  f32x4 acc[FM][FN];
  #pragma unroll
  for (int i = 0; i < FM; i++)
    #pragma unroll
    for (int j = 0; j < FN; j++)
      acc[i][j] = (f32x4){0.f, 0.f, 0.f, 0.f};

  const int arow_t = t >> 2, acol_t = (t & 3) * 8;

  for (int k0 = 0; k0 < K; k0 += 32){
    #pragma unroll
    for (int r = 0; r < BM / 64; r++){
      const _Float16* gp = A + (row0 + r*64 + arow_t) * (long)lda + k0 + acol_t;
      GLOAD16(gp, (char*)Asl + r*4096 + wid*1024);
    }
    #pragma unroll
    for (int r = 0; r < BN / 64; r++){
      const _Float16* gp = B + (col0 + r*64 + arow_t) * (long)ldb + k0 + acol_t;
      GLOAD16(gp, (char*)Bsl + r*4096 + wid*1024);
    }
    __syncthreads();
    half8 af[FM], bfv[FN];
    #pragma unroll
    for (int i = 0; i < FM; i++)
      af[i] = *(const half8*)((const char*)Asl + (wr*(BM/2) + i*16 + lr)*64 + kg*16);
    #pragma unroll
    for (int j = 0; j < FN; j++)
      bfv[j] = *(const half8*)((const char*)Bsl + (wc*(BN/2) + j*16 + lr)*64 + kg*16);
    #pragma unroll
    for (int i = 0; i < FM; i++)
      #pragma unroll
      for (int j = 0; j < FN; j++)
        acc[i][j] = __builtin_amdgcn_mfma_f32_16x16x32_f16(af[i], bfv[j], acc[i][j], 0, 0, 0);
    __syncthreads();
  }

  _Float16* Ch = (_Float16*)Cv + (long)blockIdx.z * scz;
  float*    Cf = (float*)Cv    + (long)blockIdx.z * scz;
  #pragma unroll
  for (int i = 0; i < FM; i++){
    #pragma unroll
    for (int j = 0; j < FN; j++){
      #pragma unroll
      for (int q = 0; q < 4; q++){
        long rr = row0 + wr*(BM/2) + i*16 + kg*4 + q;
        long cc = col0 + wc*(BN/2) + j*16 + lr;
        float val = acc[i][j][q] * alpha;
        if (bias) val += bias[cc];
        if constexpr (ACT) val = 0.5f * val * (1.0f + erff(val * 0.70710678118654752f));
        if constexpr (OUT_F16) Ch[rr*(long)ldc + cc] = (_Float16)val;
        else                   Cf[rr*(long)ldc + cc] = val;
      }
    }
  }
}

// ======== fused flash local attention, KV-split: unnormalized partials ========
// QBLK=64, KT=64, D=256, 4 KV-splits x 1024 rows. grid = 512.
// xcd = bid&7 = batch*4+split (1MB K/V working set per XCD); qb = bid>>3.
__global__ __launch_bounds__(256) void flash_local(
    const _Float16* __restrict__ Qb,   // qkv_l + 0   (row stride 768)
    const _Float16* __restrict__ Kb,   // qkv_l + 256 (row stride 768)
    const _Float16* __restrict__ Vt,   // [2][256][4096]
    float* __restrict__ Opart,         // [2][4][4096][256] f32 unnormalized
    float2* __restrict__ mlbuf,        // [2][4][4096] (m,l)
    float scale)
{
  __shared__ __align__(16) _Float16 Kl[64*256];   // 32KB
  __shared__ __align__(16) _Float16 Vl[256*64];   // 32KB
  __shared__ __align__(16) _Float16 Pl[64*64];    // 8KB
  __shared__ float rmax[2][64];
  __shared__ float rsum[2][64];

  const int t = threadIdx.x, wid = t >> 6, lane = t & 63;
  const int wr = wid >> 1, wc = wid & 1;
  const int g = lane >> 4, lr = lane & 15;

  const int bid = blockIdx.x;
  const int xcd = bid & 7;
  const int batch = xcd >> 2;
  const int split = xcd & 3;
  const int qb = bid >> 3;                        // 0..63
  const long QZe = (long)4096 * 768;
  const _Float16* Q = Qb + (long)batch * QZe;
  const _Float16* K = Kb + (long)batch * QZe;
  const _Float16* V = Vt + (long)batch * ((long)256 * 4096);
  const int q0 = qb * 64;

  half8 qf[2][8];
  #pragma unroll
  for (int i = 0; i < 2; i++){
    const _Float16* qp = Q + (long)(q0 + wr*32 + i*16 + lr) * 768 + g*8;
    #pragma unroll
    for (int ks = 0; ks < 8; ks++)
      qf[i][ks] = *(const half8*)(qp + ks*32);
  }

  float m_run[2][4], l_run[2][4];
  f32x4 acco[2][8];
  #pragma unroll
  for (int i = 0; i < 2; i++)
    #pragma unroll
    for (int q = 0; q < 4; q++){ m_run[i][q] = -3.0e38f; l_run[i][q] = 0.f; }
  #pragma unroll
  for (int i = 0; i < 2; i++)
    #pragma unroll
    for (int f = 0; f < 8; f++)
      acco[i][f] = (f32x4){0.f, 0.f, 0.f, 0.f};

  for (int kt = split*16; kt < split*16 + 16; kt++){
    const int kv0 = kt * 64;
    #pragma unroll
    for (int i = 0; i < 8; i++){
      int L = i*256 + t;
      int r = L >> 5, c = L & 31;
      const _Float16* gp = K + (long)(kv0 + r)*768 + ((c ^ (r & 7)) * 8);
      GLOAD16(gp, (char*)Kl + (i*256 + wid*64)*16);
    }
    #pragma unroll
    for (int i = 0; i < 8; i++){
      int L = i*256 + t;
      int d = L >> 3, c = L & 7;
      const _Float16* gp = V + (long)d*4096 + kv0 + ((c ^ (d & 7)) * 8);
      GLOAD16(gp, (char*)Vl + (i*256 + wid*64)*16);
    }
    __syncthreads();

    f32x4 accs[2][2];
    #pragma unroll
    for (int i = 0; i < 2; i++)
      #pragma unroll
      for (int j = 0; j < 2; j++)
        accs[i][j] = (f32x4){0.f, 0.f, 0.f, 0.f};
    #pragma unroll
    for (int ks = 0; ks < 8; ks++){
      #pragma unroll
      for (int j = 0; j < 2; j++){
        int n = wc*32 + j*16 + lr;
        int c = (ks*4 + g) ^ (n & 7);
        half8 kf = *(const half8*)((const char*)Kl + n*512 + c*16);
        accs[0][j] = __builtin_amdgcn_mfma_f32_16x16x32_f16(qf[0][ks], kf, accs[0][j], 0, 0, 0);
        accs[1][j] = __builtin_amdgcn_mfma_f32_16x16x32_f16(qf[1][ks], kf, accs[1][j], 0, 0, 0);
      }
    }
    #pragma unroll
    for (int i = 0; i < 2; i++)
      #pragma unroll
      for (int j = 0; j < 2; j++)
        #pragma unroll
        for (int q = 0; q < 4; q++)
          accs[i][j][q] *= scale;

    float tmax[2][4];
    #pragma unroll
    for (int i = 0; i < 2; i++)
      #pragma unroll
      for (int q = 0; q < 4; q++)
        tmax[i][q] = fmaxf(accs[i][0][q], accs[i][1][q]);
    #pragma unroll
    for (int o = 1; o < 16; o <<= 1)
      #pragma unroll
      for (int i = 0; i < 2; i++)
        #pragma unroll
        for (int q = 0; q < 4; q++)
          tmax[i][q] = fmaxf(tmax[i][q], __shfl_xor(tmax[i][q], o));
    if (lr == 0){
      #pragma unroll
      for (int i = 0; i < 2; i++)
        #pragma unroll
        for (int q = 0; q < 4; q++)
          rmax[wc][wr*32 + i*16 + g*4 + q] = tmax[i][q];
    }
    __syncthreads();

    float alpha[2][4], tsum[2][4];
    #pragma unroll
    for (int i = 0; i < 2; i++)
      #pragma unroll
      for (int q = 0; q < 4; q++){
        int row = wr*32 + i*16 + g*4 + q;
        float tm = fmaxf(rmax[0][row], rmax[1][row]);
        float mn = fmaxf(m_run[i][q], tm);
        alpha[i][q] = expf(m_run[i][q] - mn);
        m_run[i][q] = mn;
      }
    #pragma unroll
    for (int i = 0; i < 2; i++)
      #pragma unroll
      for (int j = 0; j < 2; j++)
        #pragma unroll
        for (int q = 0; q < 4; q++)
          accs[i][j][q] = expf(accs[i][j][q] - m_run[i][q]);
    #pragma unroll
    for (int i = 0; i < 2; i++)
      #pragma unroll
      for (int q = 0; q < 4; q++)
        tsum[i][q] = accs[i][0][q] + accs[i][1][q];
    #pragma unroll
    for (int o = 1; o < 16; o <<= 1)
      #pragma unroll
      for (int i = 0; i < 2; i++)
        #pragma unroll
        for (int q = 0; q < 4; q++)
          tsum[i][q] += __shfl_xor(tsum[i][q], o);
    if (lr == 0){
      #pragma unroll
      for (int i = 0; i < 2; i++)
        #pragma unroll
        for (int q = 0; q < 4; q++)
          rsum[wc][wr*32 + i*16 + g*4 + q] = tsum[i][q];
    }
    #pragma unroll
    for (int i = 0; i < 2; i++)
      #pragma unroll
      for (int j = 0; j < 2; j++)
        #pragma unroll
        for (int q = 0; q < 4; q++){
          int row = wr*32 + i*16 + g*4 + q;
          int col = wc*32 + j*16 + lr;
          int cb = col * 2;
          int byte = row*128 + (((cb >> 4) ^ (row & 7)) << 4) + (cb & 15);
          *(_Float16*)((char*)Pl + byte) = (_Float16)accs[i][j][q];
        }
    __syncthreads();

    #pragma unroll
    for (int i = 0; i < 2; i++)
      #pragma unroll
      for (int q = 0; q < 4; q++){
        int row = wr*32 + i*16 + g*4 + q;
        l_run[i][q] = l_run[i][q]*alpha[i][q] + (rsum[0][row] + rsum[1][row]);
      }
    #pragma unroll
    for (int i = 0; i < 2; i++)
      #pragma unroll
      for (int f = 0; f < 8; f++)
        #pragma unroll
        for (int q = 0; q < 4; q++)
          acco[i][f][q] *= alpha[i][q];

    #pragma unroll
    for (int kk = 0; kk < 2; kk++){
      half8 pa[2];
      #pragma unroll
      for (int i = 0; i < 2; i++){
        int rA = wr*32 + i*16 + lr;
        int c = (kk*4 + g) ^ (rA & 7);
        pa[i] = *(const half8*)((const char*)Pl + rA*128 + c*16);
      }
      #pragma unroll
      for (int f = 0; f < 8; f++){
        int d = wc*128 + f*16 + lr;
        int c = (kk*4 + g) ^ (d & 7);
        half8 vb = *(const half8*)((const char*)Vl + d*128 + c*16);
        acco[0][f] = __builtin_amdgcn_mfma_f32_16x16x32_f16(pa[0], vb, acco[0][f], 0, 0, 0);
        acco[1][f] = __builtin_amdgcn_mfma_f32_16x16x32_f16(pa[1], vb, acco[1][f], 0, 0, 0);
      }
    }
    __syncthreads();
  }

  // ---- epilogue: unnormalized O + (m,l) partials ----
  float* Op = Opart + ((long)(batch*4 + split)*4096 + q0) * 256;
  #pragma unroll
  for (int i = 0; i < 2; i++)
    #pragma unroll
    for (int f = 0; f < 8; f++)
      #pragma unroll
      for (int q = 0; q < 4; q++){
        int row = wr*32 + i*16 + g*4 + q;
        int col = wc*128 + f*16 + lr;
        Op[(long)row*256 + col] = acco[i][f][q];
      }
  if (wc == 0 && lr == 0){
    #pragma unroll
    for (int i = 0; i < 2; i++)
      #pragma unroll
      for (int q = 0; q < 4; q++){
        int row = wr*32 + i*16 + g*4 + q;
        mlbuf[(long)(batch*4 + split)*4096 + q0 + row] = make_float2(m_run[i][q], l_run[i][q]);
      }
  }
}

// ======== combine 4 flash KV-split partials -> f16 comb cols 0:256 ========
// block = 4 rows x 64 thread-cols (float4 each); grid = 2048.
__global__ __launch_bounds__(256) void combine_flash(
    const float* __restrict__ Opart, const float2* __restrict__ mlbuf,
    _Float16* __restrict__ comb)
{
  const int rid = blockIdx.x*4 + (threadIdx.x >> 6);   // 0..8191
  const int c4 = threadIdx.x & 63;
  const int batch = rid >> 12, row = rid & 4095;
  float2 ml[4];
  float m = -3.0e38f;
  #pragma unroll
  for (int s = 0; s < 4; s++){
    ml[s] = mlbuf[(long)(batch*4 + s)*4096 + row];
    m = fmaxf(m, ml[s].x);
  }
  float l = 0.f, w[4];
  #pragma unroll
  for (int s = 0; s < 4; s++){
    w[s] = expf(ml[s].x - m);
    l += w[s] * ml[s].y;
  }
  const float4* O4 = (const float4*)Opart;
  float4 o = (float4){0.f,0.f,0.f,0.f};
  #pragma unroll
  for (int s = 0; s < 4; s++){
    float4 p = O4[((long)(batch*4 + s)*4096 + row)*64 + c4];
    o.x += w[s]*p.x; o.y += w[s]*p.y; o.z += w[s]*p.z; o.w += w[s]*p.w;
  }
  const float inv = 1.0f / l;
  half4v r;
  r[0] = (_Float16)(o.x*inv); r[1] = (_Float16)(o.y*inv);
  r[2] = (_Float16)(o.z*inv); r[3] = (_Float16)(o.w*inv);
  *(half4v*)(comb + ((long)batch*4096 + row)*1024 + c4*4) = r;
}

// ======== split-K PV GEMM, BN=256 full width: f32 partials ========
template<int BM, int BN>
__global__ __launch_bounds__(256) void gemm_pv(
    const _Float16* __restrict__ A, long saz, int lda,
    const _Float16* __restrict__ B, long sbz, int ldb,
    float* __restrict__ P, int nsplit, int Ksplit)
{
  constexpr int FM = BM / 32, FN = BN / 32;
  __shared__ __align__(16) _Float16 Asl[BM * 32];
  __shared__ __align__(16) _Float16 Bsl[BN * 32];
  const int t = threadIdx.x;
  const int wid = t >> 6, lane = t & 63;
  const int wr = wid >> 1, wc = wid & 1;
  const int lr = lane & 15, kg = lane >> 4;
  const int z = blockIdx.z, batch = z / nsplit, split = z % nsplit;
  A += (long)batch * saz;
  B += (long)batch * sbz;
  float* Pz = P + (size_t)z * (4096 * 256);
  const long row0 = (long)blockIdx.y * BM;
  const int Kbase = split * Ksplit;

  f32x4 acc[FM][FN];
  #pragma unroll
  for (int i = 0; i < FM; i++)
    #pragma unroll
    for (int j = 0; j < FN; j++)
      acc[i][j] = (f32x4){0.f, 0.f, 0.f, 0.f};

  const int arow_t = t >> 2, acol_t = (t & 3) * 8;

  for (int k0 = 0; k0 < Ksplit; k0 += 32){
    #pragma unroll
    for (int r = 0; r < BM / 64; r++){
      const _Float16* gp = A + (row0 + r*64 + arow_t) * (long)lda + Kbase + k0 + acol_t;
      GLOAD16(gp, (char*)Asl + r*4096 + wid*1024);
    }
    #pragma unroll
    for (int r = 0; r < BN / 64; r++){
      const _Float16* gp = B + (r*64 + arow_t) * (long)ldb + Kbase + k0 + acol_t;
      GLOAD16(gp, (char*)Bsl + r*4096 + wid*1024);
    }
    __syncthreads();
    half8 af[FM], bfv[FN];
    #pragma unroll
    for (int i = 0; i < FM; i++)
      af[i] = *(const half8*)((const char*)Asl + (wr*(BM/2) + i*16 + lr)*64 + kg*16);
    #pragma unroll
    for (int j = 0; j < FN; j++)
      bfv[j] = *(const half8*)((const char*)Bsl + (wc*(BN/2) + j*16 + lr)*64 + kg*16);
    #pragma unroll
    for (int i = 0; i < FM; i++)
      #pragma unroll
      for (int j = 0; j < FN; j++)
        acc[i][j] = __builtin_amdgcn_mfma_f32_16x16x32_f16(af[i], bfv[j], acc[i][j], 0, 0, 0);
    __syncthreads();
  }

  #pragma unroll
  for (int i = 0; i < FM; i++)
    #pragma unroll
    for (int j = 0; j < FN; j++)
      #pragma unroll
      for (int q = 0; q < 4; q++){
        long rr = row0 + wr*(BM/2) + i*16 + kg*4 + q;
        long cc = wc*(BN/2) + j*16 + lr;
        Pz[rr*256 + cc] = acc[i][j][q];
      }
}

// ======== sum 4 split-K partials -> f16 into comb at column offset ========
__global__ __launch_bounds__(256) void reduce4(const float* __restrict__ P,
                                               _Float16* __restrict__ dst, int coff, int nq){
  int i = blockIdx.x * 256 + threadIdx.x;
  if (i >= nq) return;
  int b = i >> 18;
  int r = i & 262143;
  int row = r >> 6, col4 = r & 63;
  const float4* P4 = (const float4*)P;
  float4 s = P4[(size_t)(b*4 + 0) * 262144 + r];
  #pragma unroll
  for (int sp = 1; sp < 4; sp++){
    float4 q = P4[(size_t)(b*4 + sp) * 262144 + r];
    s.x += q.x; s.y += q.y; s.z += q.z; s.w += q.w;
  }
  half4v o;
  o[0] = (_Float16)s.x; o[1] = (_Float16)s.y; o[2] = (_Float16)s.z; o[3] = (_Float16)s.w;
  *(half4v*)(dst + ((size_t)b*4096 + row)*1024 + coff + col4*4) = o;
}

// ======== cast f32 -> f16 (8 elems/thread) ========
__global__ __launch_bounds__(256) void cast_xh(const float* __restrict__ in,
                                               _Float16* __restrict__ out, int n8){
  int i = blockIdx.x * 256 + threadIdx.x;
  const int stride = gridDim.x * 256;
  for (; i < n8; i += stride){
    float4 a = ((const float4*)in)[2*i];
    float4 b = ((const float4*)in)[2*i + 1];
    half8 o;
    o[0]=(_Float16)a.x; o[1]=(_Float16)a.y; o[2]=(_Float16)a.z; o[3]=(_Float16)a.w;
    o[4]=(_Float16)b.x; o[5]=(_Float16)b.y; o[6]=(_Float16)b.z; o[7]=(_Float16)b.w;
    *(half8*)(out + (size_t)i*8) = o;
  }
}

// ======== transpose+cast weight: in (R x C) f32 -> out (C x R) f16 ========
__global__ __launch_bounds__(256) void transpose_cast_w(const float* __restrict__ in, int R, int C,
                                                        _Float16* __restrict__ out){
  __shared__ float tile[32][33];
  const int c0 = blockIdx.x * 32, r0 = blockIdx.y * 32;
  const int tx = threadIdx.x & 31, ty = threadIdx.x >> 5;
  #pragma unroll
  for (int i = 0; i < 32; i += 8)
    tile[ty+i][tx] = in[(size_t)(r0+ty+i)*C + c0+tx];
  __syncthreads();
  #pragma unroll
  for (int i = 0; i < 32; i += 8)
    out[(size_t)(c0+ty+i)*R + r0+tx] = (_Float16)tile[tx][ty+i];
}

// ======== f16 transpose: in (R x C, ld_in) -> out (C x R, ld_out), z-batched ========
__global__ __launch_bounds__(256) void transpose_h(
    const _Float16* __restrict__ in, long in_z, int ld_in,
    _Float16* __restrict__ out, long out_z, int ld_out)
{
  __shared__ _Float16 tile[32][34];
  const _Float16* ip = in + (long)blockIdx.z * in_z;
  _Float16* op = out + (long)blockIdx.z * out_z;
  const int c0 = blockIdx.x * 32, r0 = blockIdx.y * 32;
  const int tx = threadIdx.x & 31, ty = threadIdx.x >> 5;
  #pragma unroll
  for (int i = 0; i < 32; i += 8)
    tile[ty+i][tx] = ip[(long)(r0+ty+i)*ld_in + c0+tx];
  __syncthreads();
  #pragma unroll
  for (int i = 0; i < 32; i += 8)
    op[(long)(c0+ty+i)*ld_out + r0+tx] = tile[tx][ty+i];
}

// ======== exact top-k (4x8-bit radix, per-wave hist + shfl scan) + masked softmax ========
__global__ __launch_bounds__(256) void sparse_softmax_inplace(float* __restrict__ sc, int ksel){
  __shared__ unsigned hist4[4][256];
  __shared__ unsigned hrev[256];
  __shared__ unsigned suf[257];
  __shared__ unsigned wtot[4];
  __shared__ int selb;
  __shared__ float red[4], red2[4];
  const int t = threadIdx.x, lane = t & 63, wid = t >> 6;
  float* p = sc + (size_t)blockIdx.x * 4096;
  float v[16]; unsigned kk[16];
  #pragma unroll
  for (int j = 0; j < 4; j++){
    float4 q = *(const float4*)(p + t*16 + j*4);
    v[4*j] = q.x; v[4*j+1] = q.y; v[4*j+2] = q.z; v[4*j+3] = q.w;
  }
  #pragma unroll
  for (int e = 0; e < 16; e++) kk[e] = f2k(v[e]);
  float m = v[0];
  #pragma unroll
  for (int e = 1; e < 16; e++) m = fmaxf(m, v[e]);
  m = wred_max(m);
  if (lane == 0) red[wid] = m;
  __syncthreads();
  m = fmaxf(fmaxf(red[0], red[1]), fmaxf(red[2], red[3]));

  unsigned prefix = 0;
  unsigned remaining = (unsigned)ksel;
  for (int pass = 0; pass < 4; ++pass){
    const int shift = 24 - 8*pass;
    ((uint4*)hist4)[t] = (uint4){0u,0u,0u,0u};
    __syncthreads();
    #pragma unroll
    for (int e = 0; e < 16; e++){
      unsigned k = kk[e];
      bool cand = (pass == 0) || ((k >> (shift + 8)) == prefix);
      if (cand) atomicAdd(&hist4[wid][(k >> shift) & 255u], 1u);
    }
    __syncthreads();
    unsigned h = hist4[0][t] + hist4[1][t] + hist4[2][t] + hist4[3][t];
    hrev[t] = h;
    __syncthreads();
    unsigned x = hrev[255 - t];
    #pragma unroll
    for (int o = 1; o < 64; o <<= 1){
      unsigned y = __shfl_up(x, o);
      if (lane >= o) x += y;
    }
    if (lane == 63) wtot[wid] = x;
    __syncthreads();
    #pragma unroll
    for (int w = 0; w < 4; w++) if (w < wid) x += wtot[w];
    suf[255 - t] = x;
    if (t == 0) suf[256] = 0u;
    __syncthreads();
    if (suf[t] >= remaining && suf[t+1] < remaining) selb = t;
    __syncthreads();
    const int b = selb;
    remaining -= suf[b+1];
    prefix = (prefix << 8) | (unsigned)b;
  }
  const unsigned Tkey = prefix;

  float ev[16];
  float s = 0.f;
  #pragma unroll
  for (int e = 0; e < 16; e++){
    ev[e] = (kk[e] >= Tkey) ? expf(v[e] - m) : 0.f;
    s += ev[e];
  }
  s = wred_sum(s);
  if (lane == 0) red2[wid] = s;
  __syncthreads();
  s = red2[0] + red2[1] + red2[2] + red2[3];
  const float inv = 1.0f / s;
  _Float16* ph = (_Float16*)p;
  half8 o0, o1;
  #pragma unroll
  for (int e = 0; e < 8; e++){
    o0[e] = (_Float16)(ev[e]   * inv);
    o1[e] = (_Float16)(ev[8+e] * inv);
  }
  *(half8*)(ph + t*16)     = o0;
  *(half8*)(ph + t*16 + 8) = o1;
}

// ======== memory-head softmax over 64 scores: one wave per row ========
__global__ __launch_bounds__(256) void msoftmax64(const float* __restrict__ mscore,
                                                  _Float16* __restrict__ mprob){
  const int t = threadIdx.x, lane = t & 63, wid = t >> 6;
  const size_t row = (size_t)blockIdx.x * 4 + wid;
  float v = mscore[row*64 + lane];
  float m = wred_max(v);
  float e = expf(v - m);
  float s = wred_sum(e);
  mprob[row*64 + lane] = (_Float16)(e / s);
}

extern "C" void kernel_launch(void* const* d_in, const int* in_sizes, int n_in,
                              void* d_out, int out_size, void* d_ws, size_t ws_size,
                              hipStream_t stream)
{
  const float* x             = (const float*)d_in[0];
  const float* local_qkv_w   = (const float*)d_in[1];
  const float* sparse_qkv_w  = (const float*)d_in[2];
  const float* memory_bank   = (const float*)d_in[3];
  const float* memory_proj_w = (const float*)d_in[4];
  const float* mem_out_w     = (const float*)d_in[5];
  const float* mem_out_b     = (const float*)d_in[6];
  const float* pred_in_w     = (const float*)d_in[7];
  const float* pred_in_b     = (const float*)d_in[8];
  const float* pred1_w       = (const float*)d_in[9];
  const float* pred1_b       = (const float*)d_in[10];
  const float* pred2_w       = (const float*)d_in[11];
  const float* pred2_b       = (const float*)d_in[12];
  const float* warboss_w     = (const float*)d_in[13];
  const float* warboss_b     = (const float*)d_in[14];
  float* out = (float*)d_out;

  char* wsb = (char*)d_ws;
  float*     scores_f = (float*)wsb;                   // sparse f32 scores (one batch)
  _Float16*  x_h      = (_Float16*)wsb;
  float*     Opart    = (float*)wsb;                   // flash partials [2][4][4096][256]
  float2*    mlbuf    = (float2*)(wsb + 35651584);     // [2][4][4096] (m,l)
  _Float16*  mem_cat  = (_Float16*)(wsb + 16777216);
  _Float16*  h_in     = (_Float16*)(wsb + 25165824);
  _Float16*  h1       = (_Float16*)(wsb + 29360128);
  float*     mscore   = (float*)(wsb + 37748736);
  _Float16*  mprob    = (_Float16*)(wsb + 39845888);
  _Float16*  qkv_l    = (_Float16*)(wsb + 67108864);   // [8192][768]
  _Float16*  qkv_s    = (_Float16*)(wsb + 79691776);   // [8192][768]
  _Float16*  Vt       = (_Float16*)(wsb + 92274688);   // [2][256][4096]
  _Float16*  comb     = (_Float16*)(wsb + 96468992);   // [8192][1024]
  _Float16*  lqkvT    = (_Float16*)(wsb + 113246208);  // [768][1024]
  _Float16*  sqkvT    = lqkvT  + 786432;
  _Float16*  mprojT   = sqkvT  + 786432;               // [256][1024]
  _Float16*  moutT    = mprojT + 262144;               // [256][512]
  _Float16*  pinT     = moutT  + 131072;               // [256][1024]
  _Float16*  p1T      = pinT   + 262144;               // [512][256]
  _Float16*  p2T      = p1T    + 131072;               // [256][512]
  _Float16*  wbT      = p2T    + 131072;               // [1024][1024]
  _Float16*  bank_h   = wbT    + 1048576;              // [64][256]
  _Float16*  bankT_h  = bank_h + 16384;                // [256][64]

  const dim3 blk(256);
  const float scale = 0.0625f;
  const long QZ  = (long)4096 * 768;
  const long VZ  = (long)256 * 4096;
  const long CZ  = (long)4096 * 1024;

  // ---- casts / weight transposes ----
  cast_xh<<<dim3(2048), blk, 0, stream>>>(x, x_h, 1048576);
  cast_xh<<<dim3(8), blk, 0, stream>>>(memory_bank, bank_h, 2048);
  transpose_cast_w<<<dim3(24,32), blk, 0, stream>>>(local_qkv_w,  1024,  768, lqkvT);
  transpose_cast_w<<<dim3(24,32), blk, 0, stream>>>(sparse_qkv_w, 1024,  768, sqkvT);
  transpose_cast_w<<<dim3( 8,32), blk, 0, stream>>>(memory_proj_w,1024,  256, mprojT);
  transpose_cast_w<<<dim3( 8,16), blk, 0, stream>>>(mem_out_w,     512,  256, moutT);
  transpose_cast_w<<<dim3( 8,32), blk, 0, stream>>>(pred_in_w,    1024,  256, pinT);
  transpose_cast_w<<<dim3(16, 8), blk, 0, stream>>>(pred1_w,       256,  512, p1T);
  transpose_cast_w<<<dim3( 8,16), blk, 0, stream>>>(pred2_w,       512,  256, p2T);
  transpose_cast_w<<<dim3(32,32), blk, 0, stream>>>(warboss_w,    1024, 1024, wbT);
  transpose_cast_w<<<dim3( 8, 2), blk, 0, stream>>>(memory_bank,    64,  256, bankT_h);

  // ---- QKV projections ----
  gemm_ht<128,128,1,0><<<dim3(6,64), blk, 0, stream>>>(x_h,0,1024, lqkvT,0,1024, qkv_l,0,768, 1024, 1.f, nullptr);
  gemm_ht<128,128,1,0><<<dim3(6,64), blk, 0, stream>>>(x_h,0,1024, sqkvT,0,1024, qkv_s,0,768, 1024, 1.f, nullptr);

  // ---- memory head (GEMM chain) -> comb[:, 512:768] ----
  gemm_ht<128,64,1,0><<<dim3(4,64), blk, 0, stream>>>(x_h,0,1024, mprojT,0,1024, mem_cat,0,512, 1024, 1.f, nullptr);
  gemm_ht<128,64,0,0><<<dim3(1,64), blk, 0, stream>>>(mem_cat,0,512, bank_h,0,256, (void*)mscore,0,64, 256, 1.f, nullptr);
  msoftmax64<<<dim3(2048), blk, 0, stream>>>(mscore, mprob);
  gemm_ht<128,64,1,0><<<dim3(4,64), blk, 0, stream>>>(mprob,0,64, bankT_h,0,64, mem_cat+256,0,512, 64, 1.f, nullptr);
  gemm_ht<128,64,1,0><<<dim3(4,64), blk, 0, stream>>>(mem_cat,0,512, moutT,0,512, comb+512,0,1024, 512, 1.f, mem_out_b);

  // ---- prediction head -> comb[:, 768:1024] ----
  gemm_ht<128,64,1,0><<<dim3(4,64), blk, 0, stream>>>(x_h,0,1024, pinT,0,1024, h_in,0,256, 1024, 1.f, pred_in_b);
  gemm_ht<128,128,1,1><<<dim3(4,64), blk, 0, stream>>>(h_in,0,256, p1T,0,256, h1,0,512, 256, 1.f, pred1_b);
  gemm_ht<128,64,1,0><<<dim3(4,64), blk, 0, stream>>>(h1,0,512, p2T,0,512, comb+768,0,1024, 512, 1.f, pred2_b);

  // ---- local (full) attention: KV-split flash -> comb[:, 0:256] ----
  transpose_h<<<dim3(8,128,2), blk, 0, stream>>>(qkv_l+512, QZ, 768, Vt, VZ, 4096);
  flash_local<<<dim3(512), blk, 0, stream>>>(qkv_l, qkv_l+256, Vt, Opart, mlbuf, scale);
  combine_flash<<<dim3(2048), blk, 0, stream>>>(Opart, mlbuf, comb);

  // ---- sparse (top-k) attention -> comb[:, 256:512]; f32 scores per batch ----
  transpose_h<<<dim3(8,128,2), blk, 0, stream>>>(qkv_s+512, QZ, 768, Vt, VZ, 4096);
  for (int b = 0; b < 2; b++){
    const _Float16* Q = qkv_s + (long)b * QZ;
    gemm_ht<128,128,0,0><<<dim3(32,32), blk, 0, stream>>>(Q,0,768, Q+256,0,768, (void*)scores_f,0,4096, 256, scale, nullptr);
    sparse_softmax_inplace<<<dim3(4096), blk, 0, stream>>>(scores_f, 409);
    gemm_pv<64,256><<<dim3(1,64,4), blk, 0, stream>>>((const _Float16*)scores_f,0,8192, Vt + (long)b*VZ,0,4096, out, 4, 1024);
    reduce4<<<dim3(1024), blk, 0, stream>>>(out, comb + (long)b*CZ, 256, 262144);
  }

  // ---- output projection (f32 out) ----
  gemm_ht<128,128,0,0><<<dim3(8,64), blk, 0, stream>>>(comb,0,1024, wbT,0,1024, (void*)out,0,1024, 1024, 1.f, warboss_b);
}

// Round 9
// 506.028 us; speedup vs baseline: 1.4173x; 1.1933x over previous
//
#include <hip/hip_runtime.h>
#include <hip/hip_bf16.h>

typedef __attribute__((ext_vector_type(8))) _Float16 half8;
typedef __attribute__((ext_vector_type(4))) _Float16 half4v;
typedef __attribute__((ext_vector_type(4))) float f32x4;

__device__ __forceinline__ float wred_max(float v){
  #pragma unroll
  for (int o = 32; o; o >>= 1) v = fmaxf(v, __shfl_xor(v, o));
  return v;
}
__device__ __forceinline__ float wred_sum(float v){
  #pragma unroll
  for (int o = 32; o; o >>= 1) v += __shfl_xor(v, o);
  return v;
}
__device__ __forceinline__ unsigned f2k(float f){
  unsigned u = __float_as_uint(f);
  return (u & 0x80000000u) ? ~u : (u | 0x80000000u);
}

#define GLOAD16(GP, LP) __builtin_amdgcn_global_load_lds( \
    (const __attribute__((address_space(1))) void*)(GP),  \
    (__attribute__((address_space(3))) void*)(LP), 16, 0, 0)

// ======== MFMA GEMM (f16 in, f32 acc): C = alpha * A(MxK) @ B(NxK)^T (+bias) ========
template<int BM, int BN, int OUT_F16, int ACT>
__global__ __launch_bounds__(256) void gemm_ht(
    const _Float16* __restrict__ A, long saz, int lda,
    const _Float16* __restrict__ B, long sbz, int ldb,
    void* __restrict__ Cv, long scz, int ldc,
    int K, float alpha, const float* __restrict__ bias)
{
  constexpr int FM = BM / 32, FN = BN / 32;
  __shared__ __align__(16) _Float16 Asl[BM * 32];
  __shared__ __align__(16) _Float16 Bsl[BN * 32];
  const int t = threadIdx.x;
  const int wid = t >> 6, lane = t & 63;
  const int wr = wid >> 1, wc = wid & 1;
  const int lr = lane & 15, kg = lane >> 4;
  A += (long)blockIdx.z * saz;
  B += (long)blockIdx.z * sbz;
  const long row0 = (long)blockIdx.y * BM;
  const long col0 = (long)blockIdx.x * BN;

  f32x4 acc[FM][FN];
  #pragma unroll
  for (int i = 0; i < FM; i++)
    #pragma unroll
    for (int j = 0; j < FN; j++)
      acc[i][j] = (f32x4){0.f, 0.f, 0.f, 0.f};

  const int arow_t = t >> 2, acol_t = (t & 3) * 8;

  for (int k0 = 0; k0 < K; k0 += 32){
    #pragma unroll
    for (int r = 0; r < BM / 64; r++){
      const _Float16* gp = A + (row0 + r*64 + arow_t) * (long)lda + k0 + acol_t;
      GLOAD16(gp, (char*)Asl + r*4096 + wid*1024);
    }
    #pragma unroll
    for (int r = 0; r < BN / 64; r++){
      const _Float16* gp = B + (col0 + r*64 + arow_t) * (long)ldb + k0 + acol_t;
      GLOAD16(gp, (char*)Bsl + r*4096 + wid*1024);
    }
    __syncthreads();
    half8 af[FM], bfv[FN];
    #pragma unroll
    for (int i = 0; i < FM; i++)
      af[i] = *(const half8*)((const char*)Asl + (wr*(BM/2) + i*16 + lr)*64 + kg*16);
    #pragma unroll
    for (int j = 0; j < FN; j++)
      bfv[j] = *(const half8*)((const char*)Bsl + (wc*(BN/2) + j*16 + lr)*64 + kg*16);
    #pragma unroll
    for (int i = 0; i < FM; i++)
      #pragma unroll
      for (int j = 0; j < FN; j++)
        acc[i][j] = __builtin_amdgcn_mfma_f32_16x16x32_f16(af[i], bfv[j], acc[i][j], 0, 0, 0);
    __syncthreads();
  }

  _Float16* Ch = (_Float16*)Cv + (long)blockIdx.z * scz;
  float*    Cf = (float*)Cv    + (long)blockIdx.z * scz;
  #pragma unroll
  for (int i = 0; i < FM; i++){
    #pragma unroll
    for (int j = 0; j < FN; j++){
      #pragma unroll
      for (int q = 0; q < 4; q++){
        long rr = row0 + wr*(BM/2) + i*16 + kg*4 + q;
        long cc = col0 + wc*(BN/2) + j*16 + lr;
        float val = acc[i][j][q] * alpha;
        if (bias) val += bias[cc];
        if constexpr (ACT) val = 0.5f * val * (1.0f + erff(val * 0.70710678118654752f));
        if constexpr (OUT_F16) Ch[rr*(long)ldc + cc] = (_Float16)val;
        else                   Cf[rr*(long)ldc + cc] = val;
      }
    }
  }
}

// ======== split-K PV GEMM, BN=256 full width (A read once): f32 partials ========
// z = batch*nsplit + split; partial z at P + z*4096*256. grid (1, 64, z).
template<int BM, int BN>
__global__ __launch_bounds__(256) void gemm_pv(
    const _Float16* __restrict__ A, long saz, int lda,
    const _Float16* __restrict__ B, long sbz, int ldb,
    float* __restrict__ P, int nsplit, int Ksplit)
{
  constexpr int FM = BM / 32, FN = BN / 32;
  __shared__ __align__(16) _Float16 Asl[BM * 32];
  __shared__ __align__(16) _Float16 Bsl[BN * 32];
  const int t = threadIdx.x;
  const int wid = t >> 6, lane = t & 63;
  const int wr = wid >> 1, wc = wid & 1;
  const int lr = lane & 15, kg = lane >> 4;
  const int z = blockIdx.z, batch = z / nsplit, split = z % nsplit;
  A += (long)batch * saz;
  B += (long)batch * sbz;
  float* Pz = P + (size_t)z * (4096 * 256);
  const long row0 = (long)blockIdx.y * BM;
  const int Kbase = split * Ksplit;

  f32x4 acc[FM][FN];
  #pragma unroll
  for (int i = 0; i < FM; i++)
    #pragma unroll
    for (int j = 0; j < FN; j++)
      acc[i][j] = (f32x4){0.f, 0.f, 0.f, 0.f};

  const int arow_t = t >> 2, acol_t = (t & 3) * 8;

  for (int k0 = 0; k0 < Ksplit; k0 += 32){
    #pragma unroll
    for (int r = 0; r < BM / 64; r++){
      const _Float16* gp = A + (row0 + r*64 + arow_t) * (long)lda + Kbase + k0 + acol_t;
      GLOAD16(gp, (char*)Asl + r*4096 + wid*1024);
    }
    #pragma unroll
    for (int r = 0; r < BN / 64; r++){
      const _Float16* gp = B + (r*64 + arow_t) * (long)ldb + Kbase + k0 + acol_t;
      GLOAD16(gp, (char*)Bsl + r*4096 + wid*1024);
    }
    __syncthreads();
    half8 af[FM], bfv[FN];
    #pragma unroll
    for (int i = 0; i < FM; i++)
      af[i] = *(const half8*)((const char*)Asl + (wr*(BM/2) + i*16 + lr)*64 + kg*16);
    #pragma unroll
    for (int j = 0; j < FN; j++)
      bfv[j] = *(const half8*)((const char*)Bsl + (wc*(BN/2) + j*16 + lr)*64 + kg*16);
    #pragma unroll
    for (int i = 0; i < FM; i++)
      #pragma unroll
      for (int j = 0; j < FN; j++)
        acc[i][j] = __builtin_amdgcn_mfma_f32_16x16x32_f16(af[i], bfv[j], acc[i][j], 0, 0, 0);
    __syncthreads();
  }

  #pragma unroll
  for (int i = 0; i < FM; i++)
    #pragma unroll
    for (int j = 0; j < FN; j++)
      #pragma unroll
      for (int q = 0; q < 4; q++){
        long rr = row0 + wr*(BM/2) + i*16 + kg*4 + q;
        long cc = wc*(BN/2) + j*16 + lr;
        Pz[rr*256 + cc] = acc[i][j][q];
      }
}

// ======== sum 4 split-K partials -> f16 into comb at column offset ========
__global__ __launch_bounds__(256) void reduce4(const float* __restrict__ P,
                                               _Float16* __restrict__ dst, int coff, int nq){
  int i = blockIdx.x * 256 + threadIdx.x;
  if (i >= nq) return;
  int b = i >> 18;
  int r = i & 262143;
  int row = r >> 6, col4 = r & 63;
  const float4* P4 = (const float4*)P;
  float4 s = P4[(size_t)(b*4 + 0) * 262144 + r];
  #pragma unroll
  for (int sp = 1; sp < 4; sp++){
    float4 q = P4[(size_t)(b*4 + sp) * 262144 + r];
    s.x += q.x; s.y += q.y; s.z += q.z; s.w += q.w;
  }
  half4v o;
  o[0] = (_Float16)s.x; o[1] = (_Float16)s.y; o[2] = (_Float16)s.z; o[3] = (_Float16)s.w;
  *(half4v*)(dst + ((size_t)b*4096 + row)*1024 + coff + col4*4) = o;
}

// ======== cast f32 -> f16 (8 elems/thread) ========
__global__ __launch_bounds__(256) void cast_xh(const float* __restrict__ in,
                                               _Float16* __restrict__ out, int n8){
  int i = blockIdx.x * 256 + threadIdx.x;
  const int stride = gridDim.x * 256;
  for (; i < n8; i += stride){
    float4 a = ((const float4*)in)[2*i];
    float4 b = ((const float4*)in)[2*i + 1];
    half8 o;
    o[0]=(_Float16)a.x; o[1]=(_Float16)a.y; o[2]=(_Float16)a.z; o[3]=(_Float16)a.w;
    o[4]=(_Float16)b.x; o[5]=(_Float16)b.y; o[6]=(_Float16)b.z; o[7]=(_Float16)b.w;
    *(half8*)(out + (size_t)i*8) = o;
  }
}

// ======== transpose+cast weight: in (R x C) f32 -> out (C x R) f16 ========
__global__ __launch_bounds__(256) void transpose_cast_w(const float* __restrict__ in, int R, int C,
                                                        _Float16* __restrict__ out){
  __shared__ float tile[32][33];
  const int c0 = blockIdx.x * 32, r0 = blockIdx.y * 32;
  const int tx = threadIdx.x & 31, ty = threadIdx.x >> 5;
  #pragma unroll
  for (int i = 0; i < 32; i += 8)
    tile[ty+i][tx] = in[(size_t)(r0+ty+i)*C + c0+tx];
  __syncthreads();
  #pragma unroll
  for (int i = 0; i < 32; i += 8)
    out[(size_t)(c0+ty+i)*R + r0+tx] = (_Float16)tile[tx][ty+i];
}

// ======== f16 transpose: in (R x C, ld_in) -> out (C x R, ld_out), z-batched ========
__global__ __launch_bounds__(256) void transpose_h(
    const _Float16* __restrict__ in, long in_z, int ld_in,
    _Float16* __restrict__ out, long out_z, int ld_out)
{
  __shared__ _Float16 tile[32][34];
  const _Float16* ip = in + (long)blockIdx.z * in_z;
  _Float16* op = out + (long)blockIdx.z * out_z;
  const int c0 = blockIdx.x * 32, r0 = blockIdx.y * 32;
  const int tx = threadIdx.x & 31, ty = threadIdx.x >> 5;
  #pragma unroll
  for (int i = 0; i < 32; i += 8)
    tile[ty+i][tx] = ip[(long)(r0+ty+i)*ld_in + c0+tx];
  __syncthreads();
  #pragma unroll
  for (int i = 0; i < 32; i += 8)
    op[(long)(c0+ty+i)*ld_out + r0+tx] = tile[tx][ty+i];
}

// ======== full softmax over a 4096-wide f16 row, in place (local head) ========
__global__ __launch_bounds__(256) void softmax_f16row(_Float16* __restrict__ sc){
  __shared__ float red[4], red2[4];
  const int t = threadIdx.x, lane = t & 63, wid = t >> 6;
  _Float16* p = sc + (size_t)blockIdx.x * 4096;
  half8 a = ((const half8*)p)[t*2];
  half8 b = ((const half8*)p)[t*2 + 1];
  float v[16];
  #pragma unroll
  for (int e = 0; e < 8; e++){ v[e] = (float)a[e]; v[8+e] = (float)b[e]; }
  float m = v[0];
  #pragma unroll
  for (int e = 1; e < 16; e++) m = fmaxf(m, v[e]);
  m = wred_max(m);
  if (lane == 0) red[wid] = m;
  __syncthreads();
  m = fmaxf(fmaxf(red[0], red[1]), fmaxf(red[2], red[3]));
  float s = 0.f;
  #pragma unroll
  for (int e = 0; e < 16; e++){ v[e] = expf(v[e] - m); s += v[e]; }
  s = wred_sum(s);
  if (lane == 0) red2[wid] = s;
  __syncthreads();
  s = red2[0] + red2[1] + red2[2] + red2[3];
  const float inv = 1.0f / s;
  half8 oa, ob;
  #pragma unroll
  for (int e = 0; e < 8; e++){ oa[e] = (_Float16)(v[e]*inv); ob[e] = (_Float16)(v[8+e]*inv); }
  ((half8*)p)[t*2]     = oa;
  ((half8*)p)[t*2 + 1] = ob;
}

// ======== exact top-k (4x8-bit radix, per-wave hist + shfl scan) + masked softmax ========
__global__ __launch_bounds__(256) void sparse_softmax_inplace(float* __restrict__ sc, int ksel){
  __shared__ unsigned hist4[4][256];
  __shared__ unsigned hrev[256];
  __shared__ unsigned suf[257];
  __shared__ unsigned wtot[4];
  __shared__ int selb;
  __shared__ float red[4], red2[4];
  const int t = threadIdx.x, lane = t & 63, wid = t >> 6;
  float* p = sc + (size_t)blockIdx.x * 4096;
  float v[16]; unsigned kk[16];
  #pragma unroll
  for (int j = 0; j < 4; j++){
    float4 q = *(const float4*)(p + t*16 + j*4);
    v[4*j] = q.x; v[4*j+1] = q.y; v[4*j+2] = q.z; v[4*j+3] = q.w;
  }
  #pragma unroll
  for (int e = 0; e < 16; e++) kk[e] = f2k(v[e]);
  float m = v[0];
  #pragma unroll
  for (int e = 1; e < 16; e++) m = fmaxf(m, v[e]);
  m = wred_max(m);
  if (lane == 0) red[wid] = m;
  __syncthreads();
  m = fmaxf(fmaxf(red[0], red[1]), fmaxf(red[2], red[3]));

  unsigned prefix = 0;
  unsigned remaining = (unsigned)ksel;
  for (int pass = 0; pass < 4; ++pass){
    const int shift = 24 - 8*pass;
    ((uint4*)hist4)[t] = (uint4){0u,0u,0u,0u};
    __syncthreads();
    #pragma unroll
    for (int e = 0; e < 16; e++){
      unsigned k = kk[e];
      bool cand = (pass == 0) || ((k >> (shift + 8)) == prefix);
      if (cand) atomicAdd(&hist4[wid][(k >> shift) & 255u], 1u);
    }
    __syncthreads();
    unsigned h = hist4[0][t] + hist4[1][t] + hist4[2][t] + hist4[3][t];
    hrev[t] = h;
    __syncthreads();
    unsigned x = hrev[255 - t];
    #pragma unroll
    for (int o = 1; o < 64; o <<= 1){
      unsigned y = __shfl_up(x, o);
      if (lane >= o) x += y;
    }
    if (lane == 63) wtot[wid] = x;
    __syncthreads();
    #pragma unroll
    for (int w = 0; w < 4; w++) if (w < wid) x += wtot[w];
    suf[255 - t] = x;
    if (t == 0) suf[256] = 0u;
    __syncthreads();
    if (suf[t] >= remaining && suf[t+1] < remaining) selb = t;
    __syncthreads();
    const int b = selb;
    remaining -= suf[b+1];
    prefix = (prefix << 8) | (unsigned)b;
  }
  const unsigned Tkey = prefix;

  float ev[16];
  float s = 0.f;
  #pragma unroll
  for (int e = 0; e < 16; e++){
    ev[e] = (kk[e] >= Tkey) ? expf(v[e] - m) : 0.f;
    s += ev[e];
  }
  s = wred_sum(s);
  if (lane == 0) red2[wid] = s;
  __syncthreads();
  s = red2[0] + red2[1] + red2[2] + red2[3];
  const float inv = 1.0f / s;
  _Float16* ph = (_Float16*)p;
  half8 o0, o1;
  #pragma unroll
  for (int e = 0; e < 8; e++){
    o0[e] = (_Float16)(ev[e]   * inv);
    o1[e] = (_Float16)(ev[8+e] * inv);
  }
  *(half8*)(ph + t*16)     = o0;
  *(half8*)(ph + t*16 + 8) = o1;
}

// ======== memory-head softmax over 64 scores: one wave per row ========
__global__ __launch_bounds__(256) void msoftmax64(const float* __restrict__ mscore,
                                                  _Float16* __restrict__ mprob){
  const int t = threadIdx.x, lane = t & 63, wid = t >> 6;
  const size_t row = (size_t)blockIdx.x * 4 + wid;
  float v = mscore[row*64 + lane];
  float m = wred_max(v);
  float e = expf(v - m);
  float s = wred_sum(e);
  mprob[row*64 + lane] = (_Float16)(e / s);
}

extern "C" void kernel_launch(void* const* d_in, const int* in_sizes, int n_in,
                              void* d_out, int out_size, void* d_ws, size_t ws_size,
                              hipStream_t stream)
{
  const float* x             = (const float*)d_in[0];
  const float* local_qkv_w   = (const float*)d_in[1];
  const float* sparse_qkv_w  = (const float*)d_in[2];
  const float* memory_bank   = (const float*)d_in[3];
  const float* memory_proj_w = (const float*)d_in[4];
  const float* mem_out_w     = (const float*)d_in[5];
  const float* mem_out_b     = (const float*)d_in[6];
  const float* pred_in_w     = (const float*)d_in[7];
  const float* pred_in_b     = (const float*)d_in[8];
  const float* pred1_w       = (const float*)d_in[9];
  const float* pred1_b       = (const float*)d_in[10];
  const float* pred2_w       = (const float*)d_in[11];
  const float* pred2_b       = (const float*)d_in[12];
  const float* warboss_w     = (const float*)d_in[13];
  const float* warboss_b     = (const float*)d_in[14];
  float* out = (float*)d_out;

  // Region A [0, 67,108,864):
  //   early scratch: x_h [0,16.8M) | mem_cat [16.8M,25.2M) | h_in [25.2M,29.4M)
  //                  | h1 [29.4M,37.75M) | mscore [37.75M,39.85M) | mprob [39.85M,40.9M)
  //   local phase:  f16 scores/probs [2][4096][4096] (64MB)
  //   sparse phase: f32 scores [4096][4096] (one batch at a time)
  char* wsb = (char*)d_ws;
  _Float16*  scores_h = (_Float16*)wsb;
  float*     scores_f = (float*)wsb;
  _Float16*  x_h      = (_Float16*)wsb;
  _Float16*  mem_cat  = (_Float16*)(wsb + 16777216);
  _Float16*  h_in     = (_Float16*)(wsb + 25165824);
  _Float16*  h1       = (_Float16*)(wsb + 29360128);
  float*     mscore   = (float*)(wsb + 37748736);
  _Float16*  mprob    = (_Float16*)(wsb + 39845888);
  _Float16*  qkv_l    = (_Float16*)(wsb + 67108864);   // [8192][768]
  _Float16*  qkv_s    = (_Float16*)(wsb + 79691776);   // [8192][768]
  _Float16*  Vt       = (_Float16*)(wsb + 92274688);   // [2][256][4096]
  _Float16*  comb     = (_Float16*)(wsb + 96468992);   // [8192][1024]
  _Float16*  lqkvT    = (_Float16*)(wsb + 113246208);  // [768][1024]
  _Float16*  sqkvT    = lqkvT  + 786432;
  _Float16*  mprojT   = sqkvT  + 786432;               // [256][1024]
  _Float16*  moutT    = mprojT + 262144;               // [256][512]
  _Float16*  pinT     = moutT  + 131072;               // [256][1024]
  _Float16*  p1T      = pinT   + 262144;               // [512][256]
  _Float16*  p2T      = p1T    + 131072;               // [256][512]
  _Float16*  wbT      = p2T    + 131072;               // [1024][1024]
  _Float16*  bank_h   = wbT    + 1048576;              // [64][256]
  _Float16*  bankT_h  = bank_h + 16384;                // [256][64]

  const dim3 blk(256);
  const float scale = 0.0625f;
  const long QZ  = (long)4096 * 768;
  const long VZ  = (long)256 * 4096;
  const long CZ  = (long)4096 * 1024;
  const long SZH = (long)4096 * 4096;

  // ---- casts / weight transposes ----
  cast_xh<<<dim3(2048), blk, 0, stream>>>(x, x_h, 1048576);
  cast_xh<<<dim3(8), blk, 0, stream>>>(memory_bank, bank_h, 2048);
  transpose_cast_w<<<dim3(24,32), blk, 0, stream>>>(local_qkv_w,  1024,  768, lqkvT);
  transpose_cast_w<<<dim3(24,32), blk, 0, stream>>>(sparse_qkv_w, 1024,  768, sqkvT);
  transpose_cast_w<<<dim3( 8,32), blk, 0, stream>>>(memory_proj_w,1024,  256, mprojT);
  transpose_cast_w<<<dim3( 8,16), blk, 0, stream>>>(mem_out_w,     512,  256, moutT);
  transpose_cast_w<<<dim3( 8,32), blk, 0, stream>>>(pred_in_w,    1024,  256, pinT);
  transpose_cast_w<<<dim3(16, 8), blk, 0, stream>>>(pred1_w,       256,  512, p1T);
  transpose_cast_w<<<dim3( 8,16), blk, 0, stream>>>(pred2_w,       512,  256, p2T);
  transpose_cast_w<<<dim3(32,32), blk, 0, stream>>>(warboss_w,    1024, 1024, wbT);
  transpose_cast_w<<<dim3( 8, 2), blk, 0, stream>>>(memory_bank,    64,  256, bankT_h);

  // ---- QKV projections (merged z=2: local / sparse) ----
  gemm_ht<128,128,1,0><<<dim3(6,64,2), blk, 0, stream>>>(x_h,0,1024, lqkvT,786432,1024,
                                                         qkv_l,6291456,768, 1024, 1.f, nullptr);

  // ---- memory head (GEMM chain) -> comb[:, 512:768] ----
  gemm_ht<64,64,1,0><<<dim3(4,128), blk, 0, stream>>>(x_h,0,1024, mprojT,0,1024, mem_cat,0,512, 1024, 1.f, nullptr);
  gemm_ht<64,64,0,0><<<dim3(1,128), blk, 0, stream>>>(mem_cat,0,512, bank_h,0,256, (void*)mscore,0,64, 256, 1.f, nullptr);
  msoftmax64<<<dim3(2048), blk, 0, stream>>>(mscore, mprob);
  gemm_ht<64,64,1,0><<<dim3(4,128), blk, 0, stream>>>(mprob,0,64, bankT_h,0,64, mem_cat+256,0,512, 64, 1.f, nullptr);
  gemm_ht<64,64,1,0><<<dim3(4,128), blk, 0, stream>>>(mem_cat,0,512, moutT,0,512, comb+512,0,1024, 512, 1.f, mem_out_b);

  // ---- prediction head -> comb[:, 768:1024] ----
  gemm_ht<64,64,1,0><<<dim3(4,128), blk, 0, stream>>>(x_h,0,1024, pinT,0,1024, h_in,0,256, 1024, 1.f, pred_in_b);
  gemm_ht<64,128,1,1><<<dim3(4,128), blk, 0, stream>>>(h_in,0,256, p1T,0,256, h1,0,512, 256, 1.f, pred1_b);
  gemm_ht<64,64,1,0><<<dim3(4,128), blk, 0, stream>>>(h1,0,512, p2T,0,512, comb+768,0,1024, 512, 1.f, pred2_b);

  // ---- local (full) attention -> comb[:, 0:256]; f16 scores, z-batched ----
  transpose_h<<<dim3(8,128,2), blk, 0, stream>>>(qkv_l+512, QZ, 768, Vt, VZ, 4096);
  gemm_ht<128,128,1,0><<<dim3(32,32,2), blk, 0, stream>>>(qkv_l,QZ,768, qkv_l+256,QZ,768,
                                                          (void*)scores_h,SZH,4096, 256, scale, nullptr);
  softmax_f16row<<<dim3(8192), blk, 0, stream>>>(scores_h);
  gemm_pv<64,256><<<dim3(1,64,8), blk, 0, stream>>>(scores_h,SZH,4096, Vt,VZ,4096, out, 4, 1024);
  reduce4<<<dim3(2048), blk, 0, stream>>>(out, comb, 0, 524288);

  // ---- sparse (top-k) attention -> comb[:, 256:512]; f32 scores per batch ----
  transpose_h<<<dim3(8,128,2), blk, 0, stream>>>(qkv_s+512, QZ, 768, Vt, VZ, 4096);
  for (int b = 0; b < 2; b++){
    const _Float16* Q = qkv_s + (long)b * QZ;
    gemm_ht<128,128,0,0><<<dim3(32,32), blk, 0, stream>>>(Q,0,768, Q+256,0,768, (void*)scores_f,0,4096, 256, scale, nullptr);
    sparse_softmax_inplace<<<dim3(4096), blk, 0, stream>>>(scores_f, 409);
    gemm_pv<64,256><<<dim3(1,64,4), blk, 0, stream>>>((const _Float16*)scores_f,0,8192, Vt + (long)b*VZ,0,4096, out, 4, 1024);
    reduce4<<<dim3(1024), blk, 0, stream>>>(out, comb + (long)b*CZ, 256, 262144);
  }

  // ---- output projection (f32 out) ----
  gemm_ht<128,128,0,0><<<dim3(8,64), blk, 0, stream>>>(comb,0,1024, wbT,0,1024, (void*)out,0,1024, 1024, 1.f, warboss_b);
}

// Round 11
// 425.555 us; speedup vs baseline: 1.6853x; 1.1891x over previous
//
#include <hip/hip_runtime.h>
#include <hip/hip_bf16.h>

typedef __attribute__((ext_vector_type(8))) _Float16 half8;
typedef __attribute__((ext_vector_type(4))) _Float16 half4v;
typedef __attribute__((ext_vector_type(4))) float f32x4;

__device__ __forceinline__ float wred_max(float v){
  #pragma unroll
  for (int o = 32; o; o >>= 1) v = fmaxf(v, __shfl_xor(v, o));
  return v;
}
__device__ __forceinline__ float wred_sum(float v){
  #pragma unroll
  for (int o = 32; o; o >>= 1) v += __shfl_xor(v, o);
  return v;
}
__device__ __forceinline__ unsigned short h2u(_Float16 h){
  unsigned short u;
  __builtin_memcpy(&u, &h, 2);
  return u;
}

#define GLOAD16(GP, LP) __builtin_amdgcn_global_load_lds( \
    (const __attribute__((address_space(1))) void*)(GP),  \
    (__attribute__((address_space(3))) void*)(LP), 16, 0, 0)

// ======== MFMA GEMM (f16 in, f32 acc): C = alpha * A(MxK) @ B(NxK)^T (+bias) ========
template<int BM, int BN, int OUT_F16, int ACT>
__global__ __launch_bounds__(256) void gemm_ht(
    const _Float16* __restrict__ A, long saz, int lda,
    const _Float16* __restrict__ B, long sbz, int ldb,
    void* __restrict__ Cv, long scz, int ldc,
    int K, float alpha, const float* __restrict__ bias)
{
  constexpr int FM = BM / 32, FN = BN / 32;
  __shared__ __align__(16) _Float16 Asl[BM * 32];
  __shared__ __align__(16) _Float16 Bsl[BN * 32];
  const int t = threadIdx.x;
  const int wid = t >> 6, lane = t & 63;
  const int wr = wid >> 1, wc = wid & 1;
  const int lr = lane & 15, kg = lane >> 4;
  A += (long)blockIdx.z * saz;
  B += (long)blockIdx.z * sbz;
  const long row0 = (long)blockIdx.y * BM;
  const long col0 = (long)blockIdx.x * BN;

  f32x4 acc[FM][FN];
  #pragma unroll
  for (int i = 0; i < FM; i++)
    #pragma unroll
    for (int j = 0; j < FN; j++)
      acc[i][j] = (f32x4){0.f, 0.f, 0.f, 0.f};

  const int arow_t = t >> 2, acol_t = (t & 3) * 8;

  for (int k0 = 0; k0 < K; k0 += 32){
    #pragma unroll
    for (int r = 0; r < BM / 64; r++){
      const _Float16* gp = A + (row0 + r*64 + arow_t) * (long)lda + k0 + acol_t;
      GLOAD16(gp, (char*)Asl + r*4096 + wid*1024);
    }
    #pragma unroll
    for (int r = 0; r < BN / 64; r++){
      const _Float16* gp = B + (col0 + r*64 + arow_t) * (long)ldb + k0 + acol_t;
      GLOAD16(gp, (char*)Bsl + r*4096 + wid*1024);
    }
    __syncthreads();
    half8 af[FM], bfv[FN];
    #pragma unroll
    for (int i = 0; i < FM; i++)
      af[i] = *(const half8*)((const char*)Asl + (wr*(BM/2) + i*16 + lr)*64 + kg*16);
    #pragma unroll
    for (int j = 0; j < FN; j++)
      bfv[j] = *(const half8*)((const char*)Bsl + (wc*(BN/2) + j*16 + lr)*64 + kg*16);
    #pragma unroll
    for (int i = 0; i < FM; i++)
      #pragma unroll
      for (int j = 0; j < FN; j++)
        acc[i][j] = __builtin_amdgcn_mfma_f32_16x16x32_f16(af[i], bfv[j], acc[i][j], 0, 0, 0);
    __syncthreads();
  }

  _Float16* Ch = (_Float16*)Cv + (long)blockIdx.z * scz;
  float*    Cf = (float*)Cv    + (long)blockIdx.z * scz;
  #pragma unroll
  for (int i = 0; i < FM; i++){
    #pragma unroll
    for (int j = 0; j < FN; j++){
      #pragma unroll
      for (int q = 0; q < 4; q++){
        long rr = row0 + wr*(BM/2) + i*16 + kg*4 + q;
        long cc = col0 + wc*(BN/2) + j*16 + lr;
        float val = acc[i][j][q] * alpha;
        if (bias) val += bias[cc];
        if constexpr (ACT) val = 0.5f * val * (1.0f + erff(val * 0.70710678118654752f));
        if constexpr (OUT_F16) Ch[rr*(long)ldc + cc] = (_Float16)val;
        else                   Cf[rr*(long)ldc + cc] = val;
      }
    }
  }
}

// ======== split-K PV GEMM, BN=256 full width (A read once): f32 partials ========
// z = batch*nsplit + split; partial z at P + z*4096*256. grid (1, 64, z).
template<int BM, int BN>
__global__ __launch_bounds__(256) void gemm_pv(
    const _Float16* __restrict__ A, long saz, int lda,
    const _Float16* __restrict__ B, long sbz, int ldb,
    float* __restrict__ P, int nsplit, int Ksplit)
{
  constexpr int FM = BM / 32, FN = BN / 32;
  __shared__ __align__(16) _Float16 Asl[BM * 32];
  __shared__ __align__(16) _Float16 Bsl[BN * 32];
  const int t = threadIdx.x;
  const int wid = t >> 6, lane = t & 63;
  const int wr = wid >> 1, wc = wid & 1;
  const int lr = lane & 15, kg = lane >> 4;
  const int z = blockIdx.z, batch = z / nsplit, split = z % nsplit;
  A += (long)batch * saz;
  B += (long)batch * sbz;
  float* Pz = P + (size_t)z * (4096 * 256);
  const long row0 = (long)blockIdx.y * BM;
  const int Kbase = split * Ksplit;

  f32x4 acc[FM][FN];
  #pragma unroll
  for (int i = 0; i < FM; i++)
    #pragma unroll
    for (int j = 0; j < FN; j++)
      acc[i][j] = (f32x4){0.f, 0.f, 0.f, 0.f};

  const int arow_t = t >> 2, acol_t = (t & 3) * 8;

  for (int k0 = 0; k0 < Ksplit; k0 += 32){
    #pragma unroll
    for (int r = 0; r < BM / 64; r++){
      const _Float16* gp = A + (row0 + r*64 + arow_t) * (long)lda + Kbase + k0 + acol_t;
      GLOAD16(gp, (char*)Asl + r*4096 + wid*1024);
    }
    #pragma unroll
    for (int r = 0; r < BN / 64; r++){
      const _Float16* gp = B + (r*64 + arow_t) * (long)ldb + Kbase + k0 + acol_t;
      GLOAD16(gp, (char*)Bsl + r*4096 + wid*1024);
    }
    __syncthreads();
    half8 af[FM], bfv[FN];
    #pragma unroll
    for (int i = 0; i < FM; i++)
      af[i] = *(const half8*)((const char*)Asl + (wr*(BM/2) + i*16 + lr)*64 + kg*16);
    #pragma unroll
    for (int j = 0; j < FN; j++)
      bfv[j] = *(const half8*)((const char*)Bsl + (wc*(BN/2) + j*16 + lr)*64 + kg*16);
    #pragma unroll
    for (int i = 0; i < FM; i++)
      #pragma unroll
      for (int j = 0; j < FN; j++)
        acc[i][j] = __builtin_amdgcn_mfma_f32_16x16x32_f16(af[i], bfv[j], acc[i][j], 0, 0, 0);
    __syncthreads();
  }

  #pragma unroll
  for (int i = 0; i < FM; i++)
    #pragma unroll
    for (int j = 0; j < FN; j++)
      #pragma unroll
      for (int q = 0; q < 4; q++){
        long rr = row0 + wr*(BM/2) + i*16 + kg*4 + q;
        long cc = wc*(BN/2) + j*16 + lr;
        Pz[rr*256 + cc] = acc[i][j][q];
      }
}

// ======== sum 4 split-K partials -> f16 into comb at column offset ========
__global__ __launch_bounds__(256) void reduce4(const float* __restrict__ P,
                                               _Float16* __restrict__ dst, int coff, int nq){
  int i = blockIdx.x * 256 + threadIdx.x;
  if (i >= nq) return;
  int b = i >> 18;
  int r = i & 262143;
  int row = r >> 6, col4 = r & 63;
  const float4* P4 = (const float4*)P;
  float4 s = P4[(size_t)(b*4 + 0) * 262144 + r];
  #pragma unroll
  for (int sp = 1; sp < 4; sp++){
    float4 q = P4[(size_t)(b*4 + sp) * 262144 + r];
    s.x += q.x; s.y += q.y; s.z += q.z; s.w += q.w;
  }
  half4v o;
  o[0] = (_Float16)s.x; o[1] = (_Float16)s.y; o[2] = (_Float16)s.z; o[3] = (_Float16)s.w;
  *(half4v*)(dst + ((size_t)b*4096 + row)*1024 + coff + col4*4) = o;
}

// ======== cast f32 -> f16 (8 elems/thread) ========
__global__ __launch_bounds__(256) void cast_xh(const float* __restrict__ in,
                                               _Float16* __restrict__ out, int n8){
  int i = blockIdx.x * 256 + threadIdx.x;
  const int stride = gridDim.x * 256;
  for (; i < n8; i += stride){
    float4 a = ((const float4*)in)[2*i];
    float4 b = ((const float4*)in)[2*i + 1];
    half8 o;
    o[0]=(_Float16)a.x; o[1]=(_Float16)a.y; o[2]=(_Float16)a.z; o[3]=(_Float16)a.w;
    o[4]=(_Float16)b.x; o[5]=(_Float16)b.y; o[6]=(_Float16)b.z; o[7]=(_Float16)b.w;
    *(half8*)(out + (size_t)i*8) = o;
  }
}

// ======== transpose+cast weight: in (R x C) f32 -> out (C x R) f16 ========
__global__ __launch_bounds__(256) void transpose_cast_w(const float* __restrict__ in, int R, int C,
                                                        _Float16* __restrict__ out){
  __shared__ float tile[32][33];
  const int c0 = blockIdx.x * 32, r0 = blockIdx.y * 32;
  const int tx = threadIdx.x & 31, ty = threadIdx.x >> 5;
  #pragma unroll
  for (int i = 0; i < 32; i += 8)
    tile[ty+i][tx] = in[(size_t)(r0+ty+i)*C + c0+tx];
  __syncthreads();
  #pragma unroll
  for (int i = 0; i < 32; i += 8)
    out[(size_t)(c0+ty+i)*R + r0+tx] = (_Float16)tile[tx][ty+i];
}

// ======== f16 transpose: in (R x C, ld_in) -> out (C x R, ld_out), z-batched ========
__global__ __launch_bounds__(256) void transpose_h(
    const _Float16* __restrict__ in, long in_z, int ld_in,
    _Float16* __restrict__ out, long out_z, int ld_out)
{
  __shared__ _Float16 tile[32][34];
  const _Float16* ip = in + (long)blockIdx.z * in_z;
  _Float16* op = out + (long)blockIdx.z * out_z;
  const int c0 = blockIdx.x * 32, r0 = blockIdx.y * 32;
  const int tx = threadIdx.x & 31, ty = threadIdx.x >> 5;
  #pragma unroll
  for (int i = 0; i < 32; i += 8)
    tile[ty+i][tx] = ip[(long)(r0+ty+i)*ld_in + c0+tx];
  __syncthreads();
  #pragma unroll
  for (int i = 0; i < 32; i += 8)
    op[(long)(c0+ty+i)*ld_out + r0+tx] = tile[tx][ty+i];
}

// ======== full softmax over a 4096-wide f16 row, in place (local head) ========
__global__ __launch_bounds__(256) void softmax_f16row(_Float16* __restrict__ sc){
  __shared__ float red[4], red2[4];
  const int t = threadIdx.x, lane = t & 63, wid = t >> 6;
  _Float16* p = sc + (size_t)blockIdx.x * 4096;
  half8 a = ((const half8*)p)[t*2];
  half8 b = ((const half8*)p)[t*2 + 1];
  float v[16];
  #pragma unroll
  for (int e = 0; e < 8; e++){ v[e] = (float)a[e]; v[8+e] = (float)b[e]; }
  float m = v[0];
  #pragma unroll
  for (int e = 1; e < 16; e++) m = fmaxf(m, v[e]);
  m = wred_max(m);
  if (lane == 0) red[wid] = m;
  __syncthreads();
  m = fmaxf(fmaxf(red[0], red[1]), fmaxf(red[2], red[3]));
  float s = 0.f;
  #pragma unroll
  for (int e = 0; e < 16; e++){ v[e] = expf(v[e] - m); s += v[e]; }
  s = wred_sum(s);
  if (lane == 0) red2[wid] = s;
  __syncthreads();
  s = red2[0] + red2[1] + red2[2] + red2[3];
  const float inv = 1.0f / s;
  half8 oa, ob;
  #pragma unroll
  for (int e = 0; e < 8; e++){ oa[e] = (_Float16)(v[e]*inv); ob[e] = (_Float16)(v[8+e]*inv); }
  ((half8*)p)[t*2]     = oa;
  ((half8*)p)[t*2 + 1] = ob;
}

// ======== exact top-k on f16 scores (2x8-bit radix on u16 keys) + masked softmax ========
// in place over a 4096-wide f16 row; selection exact w.r.t. the stored f16 scores.
__global__ __launch_bounds__(256) void sparse_softmax16(_Float16* __restrict__ sc, int ksel){
  __shared__ unsigned hist4[4][256];
  __shared__ unsigned hrev[256];
  __shared__ unsigned suf[257];
  __shared__ unsigned wtot[4];
  __shared__ int selb;
  __shared__ float red[4], red2[4];
  const int t = threadIdx.x, lane = t & 63, wid = t >> 6;
  _Float16* p = sc + (size_t)blockIdx.x * 4096;
  half8 a = ((const half8*)p)[t*2];
  half8 b = ((const half8*)p)[t*2 + 1];
  float v[16]; unsigned kk[16];
  #pragma unroll
  for (int e = 0; e < 8; e++){
    unsigned short u0 = h2u(a[e]);
    unsigned short u1 = h2u(b[e]);
    kk[e]   = (u0 & 0x8000u) ? (unsigned)(unsigned short)~u0 : (unsigned)(u0 | 0x8000u);
    kk[8+e] = (u1 & 0x8000u) ? (unsigned)(unsigned short)~u1 : (unsigned)(u1 | 0x8000u);
    v[e] = (float)a[e]; v[8+e] = (float)b[e];
  }
  float m = v[0];
  #pragma unroll
  for (int e = 1; e < 16; e++) m = fmaxf(m, v[e]);
  m = wred_max(m);
  if (lane == 0) red[wid] = m;
  __syncthreads();
  m = fmaxf(fmaxf(red[0], red[1]), fmaxf(red[2], red[3]));

  // ---- pass 1: high byte ----
  ((uint4*)hist4)[t] = (uint4){0u,0u,0u,0u};
  __syncthreads();
  #pragma unroll
  for (int e = 0; e < 16; e++) atomicAdd(&hist4[wid][kk[e] >> 8], 1u);
  __syncthreads();
  {
    unsigned h = hist4[0][t] + hist4[1][t] + hist4[2][t] + hist4[3][t];
    hrev[t] = h;
  }
  __syncthreads();
  unsigned x = hrev[255 - t];
  #pragma unroll
  for (int o = 1; o < 64; o <<= 1){
    unsigned y = __shfl_up(x, o);
    if (lane >= o) x += y;
  }
  if (lane == 63) wtot[wid] = x;
  __syncthreads();
  #pragma unroll
  for (int w = 0; w < 4; w++) if (w < wid) x += wtot[w];
  suf[255 - t] = x;
  if (t == 0) suf[256] = 0u;
  __syncthreads();
  const unsigned ku = (unsigned)ksel;
  if (suf[t] >= ku && suf[t+1] < ku) selb = t;
  __syncthreads();
  const int b1 = selb;
  const unsigned rem = ku - suf[b1+1];
  __syncthreads();

  // ---- pass 2: low byte among high==b1 ----
  ((uint4*)hist4)[t] = (uint4){0u,0u,0u,0u};
  __syncthreads();
  #pragma unroll
  for (int e = 0; e < 16; e++)
    if ((int)(kk[e] >> 8) == b1) atomicAdd(&hist4[wid][kk[e] & 255u], 1u);
  __syncthreads();
  {
    unsigned h = hist4[0][t] + hist4[1][t] + hist4[2][t] + hist4[3][t];
    hrev[t] = h;
  }
  __syncthreads();
  x = hrev[255 - t];
  #pragma unroll
  for (int o = 1; o < 64; o <<= 1){
    unsigned y = __shfl_up(x, o);
    if (lane >= o) x += y;
  }
  if (lane == 63) wtot[wid] = x;
  __syncthreads();
  #pragma unroll
  for (int w = 0; w < 4; w++) if (w < wid) x += wtot[w];
  suf[255 - t] = x;
  if (t == 0) suf[256] = 0u;
  __syncthreads();
  if (suf[t] >= rem && suf[t+1] < rem) selb = t;
  __syncthreads();
  const unsigned Tkey = ((unsigned)b1 << 8) | (unsigned)selb;

  float ev[16];
  float s = 0.f;
  #pragma unroll
  for (int e = 0; e < 16; e++){
    ev[e] = (kk[e] >= Tkey) ? expf(v[e] - m) : 0.f;
    s += ev[e];
  }
  s = wred_sum(s);
  if (lane == 0) red2[wid] = s;
  __syncthreads();
  s = red2[0] + red2[1] + red2[2] + red2[3];
  const float inv = 1.0f / s;
  half8 o0, o1;
  #pragma unroll
  for (int e = 0; e < 8; e++){
    o0[e] = (_Float16)(ev[e]   * inv);
    o1[e] = (_Float16)(ev[8+e] * inv);
  }
  ((half8*)p)[t*2]     = o0;
  ((half8*)p)[t*2 + 1] = o1;
}

// ======== memory-head softmax over 64 scores: one wave per row ========
__global__ __launch_bounds__(256) void msoftmax64(const float* __restrict__ mscore,
                                                  _Float16* __restrict__ mprob){
  const int t = threadIdx.x, lane = t & 63, wid = t >> 6;
  const size_t row = (size_t)blockIdx.x * 4 + wid;
  float v = mscore[row*64 + lane];
  float m = wred_max(v);
  float e = expf(v - m);
  float s = wred_sum(e);
  mprob[row*64 + lane] = (_Float16)(e / s);
}

extern "C" void kernel_launch(void* const* d_in, const int* in_sizes, int n_in,
                              void* d_out, int out_size, void* d_ws, size_t ws_size,
                              hipStream_t stream)
{
  const float* x             = (const float*)d_in[0];
  const float* local_qkv_w   = (const float*)d_in[1];
  const float* sparse_qkv_w  = (const float*)d_in[2];
  const float* memory_bank   = (const float*)d_in[3];
  const float* memory_proj_w = (const float*)d_in[4];
  const float* mem_out_w     = (const float*)d_in[5];
  const float* mem_out_b     = (const float*)d_in[6];
  const float* pred_in_w     = (const float*)d_in[7];
  const float* pred_in_b     = (const float*)d_in[8];
  const float* pred1_w       = (const float*)d_in[9];
  const float* pred1_b       = (const float*)d_in[10];
  const float* pred2_w       = (const float*)d_in[11];
  const float* pred2_b       = (const float*)d_in[12];
  const float* warboss_w     = (const float*)d_in[13];
  const float* warboss_b     = (const float*)d_in[14];
  float* out = (float*)d_out;

  // Region A [0, 67,108,864):
  //   early scratch: x_h | mem_cat | h_in | h1 | mscore | mprob
  //   local phase:  f16 scores/probs [2][4096][4096] (64MB)
  //   sparse phase: f16 scores/probs [2][4096][4096] (64MB)
  char* wsb = (char*)d_ws;
  _Float16*  scores_h = (_Float16*)wsb;
  _Float16*  x_h      = (_Float16*)wsb;
  _Float16*  mem_cat  = (_Float16*)(wsb + 16777216);
  _Float16*  h_in     = (_Float16*)(wsb + 25165824);
  _Float16*  h1       = (_Float16*)(wsb + 29360128);
  float*     mscore   = (float*)(wsb + 37748736);
  _Float16*  mprob    = (_Float16*)(wsb + 39845888);
  _Float16*  qkv_l    = (_Float16*)(wsb + 67108864);   // [8192][768]
  _Float16*  qkv_s    = (_Float16*)(wsb + 79691776);   // [8192][768]
  _Float16*  Vt       = (_Float16*)(wsb + 92274688);   // [2][256][4096]
  _Float16*  comb     = (_Float16*)(wsb + 96468992);   // [8192][1024]
  _Float16*  lqkvT    = (_Float16*)(wsb + 113246208);  // [768][1024]
  _Float16*  sqkvT    = lqkvT  + 786432;
  _Float16*  mprojT   = sqkvT  + 786432;               // [256][1024]
  _Float16*  moutT    = mprojT + 262144;               // [256][512]
  _Float16*  pinT     = moutT  + 131072;               // [256][1024]
  _Float16*  p1T      = pinT   + 262144;               // [512][256]
  _Float16*  p2T      = p1T    + 131072;               // [256][512]
  _Float16*  wbT      = p2T    + 131072;               // [1024][1024]
  _Float16*  bank_h   = wbT    + 1048576;              // [64][256]
  _Float16*  bankT_h  = bank_h + 16384;                // [256][64]

  const dim3 blk(256);
  const float scale = 0.0625f;
  const long QZ  = (long)4096 * 768;
  const long VZ  = (long)256 * 4096;
  const long SZH = (long)4096 * 4096;

  // ---- casts / weight transposes ----
  cast_xh<<<dim3(2048), blk, 0, stream>>>(x, x_h, 1048576);
  cast_xh<<<dim3(8), blk, 0, stream>>>(memory_bank, bank_h, 2048);
  transpose_cast_w<<<dim3(24,32), blk, 0, stream>>>(local_qkv_w,  1024,  768, lqkvT);
  transpose_cast_w<<<dim3(24,32), blk, 0, stream>>>(sparse_qkv_w, 1024,  768, sqkvT);
  transpose_cast_w<<<dim3( 8,32), blk, 0, stream>>>(memory_proj_w,1024,  256, mprojT);
  transpose_cast_w<<<dim3( 8,16), blk, 0, stream>>>(mem_out_w,     512,  256, moutT);
  transpose_cast_w<<<dim3( 8,32), blk, 0, stream>>>(pred_in_w,    1024,  256, pinT);
  transpose_cast_w<<<dim3(16, 8), blk, 0, stream>>>(pred1_w,       256,  512, p1T);
  transpose_cast_w<<<dim3( 8,16), blk, 0, stream>>>(pred2_w,       512,  256, p2T);
  transpose_cast_w<<<dim3(32,32), blk, 0, stream>>>(warboss_w,    1024, 1024, wbT);
  transpose_cast_w<<<dim3( 8, 2), blk, 0, stream>>>(memory_bank,    64,  256, bankT_h);

  // ---- QKV projections (merged z=2: local / sparse) ----
  gemm_ht<128,128,1,0><<<dim3(6,64,2), blk, 0, stream>>>(x_h,0,1024, lqkvT,786432,1024,
                                                         qkv_l,6291456,768, 1024, 1.f, nullptr);

  // ---- memory head (GEMM chain) -> comb[:, 512:768] ----
  gemm_ht<64,64,1,0><<<dim3(4,128), blk, 0, stream>>>(x_h,0,1024, mprojT,0,1024, mem_cat,0,512, 1024, 1.f, nullptr);
  gemm_ht<64,64,0,0><<<dim3(1,128), blk, 0, stream>>>(mem_cat,0,512, bank_h,0,256, (void*)mscore,0,64, 256, 1.f, nullptr);
  msoftmax64<<<dim3(2048), blk, 0, stream>>>(mscore, mprob);
  gemm_ht<64,64,1,0><<<dim3(4,128), blk, 0, stream>>>(mprob,0,64, bankT_h,0,64, mem_cat+256,0,512, 64, 1.f, nullptr);
  gemm_ht<64,64,1,0><<<dim3(4,128), blk, 0, stream>>>(mem_cat,0,512, moutT,0,512, comb+512,0,1024, 512, 1.f, mem_out_b);

  // ---- prediction head -> comb[:, 768:1024] ----
  gemm_ht<64,64,1,0><<<dim3(4,128), blk, 0, stream>>>(x_h,0,1024, pinT,0,1024, h_in,0,256, 1024, 1.f, pred_in_b);
  gemm_ht<64,128,1,1><<<dim3(4,128), blk, 0, stream>>>(h_in,0,256, p1T,0,256, h1,0,512, 256, 1.f, pred1_b);
  gemm_ht<64,64,1,0><<<dim3(4,128), blk, 0, stream>>>(h1,0,512, p2T,0,512, comb+768,0,1024, 512, 1.f, pred2_b);

  // ---- local (full) attention -> comb[:, 0:256]; f16 scores, z-batched ----
  transpose_h<<<dim3(8,128,2), blk, 0, stream>>>(qkv_l+512, QZ, 768, Vt, VZ, 4096);
  gemm_ht<128,128,1,0><<<dim3(32,32,2), blk, 0, stream>>>(qkv_l,QZ,768, qkv_l+256,QZ,768,
                                                          (void*)scores_h,SZH,4096, 256, scale, nullptr);
  softmax_f16row<<<dim3(8192), blk, 0, stream>>>(scores_h);
  gemm_pv<64,256><<<dim3(1,64,8), blk, 0, stream>>>(scores_h,SZH,4096, Vt,VZ,4096, out, 4, 1024);
  reduce4<<<dim3(2048), blk, 0, stream>>>(out, comb, 0, 524288);

  // ---- sparse (top-k) attention -> comb[:, 256:512]; f16 scores, z-batched ----
  transpose_h<<<dim3(8,128,2), blk, 0, stream>>>(qkv_s+512, QZ, 768, Vt, VZ, 4096);
  gemm_ht<128,128,1,0><<<dim3(32,32,2), blk, 0, stream>>>(qkv_s,QZ,768, qkv_s+256,QZ,768,
                                                          (void*)scores_h,SZH,4096, 256, scale, nullptr);
  sparse_softmax16<<<dim3(8192), blk, 0, stream>>>(scores_h, 409);
  gemm_pv<64,256><<<dim3(1,64,8), blk, 0, stream>>>(scores_h,SZH,4096, Vt,VZ,4096, out, 4, 1024);
  reduce4<<<dim3(2048), blk, 0, stream>>>(out, comb, 256, 524288);

  // ---- output projection (f32 out) ----
  gemm_ht<128,128,0,0><<<dim3(8,64), blk, 0, stream>>>(comb,0,1024, wbT,0,1024, (void*)out,0,1024, 1024, 1.f, warboss_b);
}

// Round 12
// 403.149 us; speedup vs baseline: 1.7789x; 1.0556x over previous
//
#include <hip/hip_runtime.h>
#include <hip/hip_bf16.h>

typedef __attribute__((ext_vector_type(8))) _Float16 half8;
typedef __attribute__((ext_vector_type(4))) _Float16 half4v;
typedef __attribute__((ext_vector_type(4))) float f32x4;

__device__ __forceinline__ float wred_max(float v){
  #pragma unroll
  for (int o = 32; o; o >>= 1) v = fmaxf(v, __shfl_xor(v, o));
  return v;
}
__device__ __forceinline__ float wred_sum(float v){
  #pragma unroll
  for (int o = 32; o; o >>= 1) v += __shfl_xor(v, o);
  return v;
}
__device__ __forceinline__ unsigned short h2u(_Float16 h){
  unsigned short u;
  __builtin_memcpy(&u, &h, 2);
  return u;
}
__device__ __forceinline__ float u2hf(unsigned short u){
  _Float16 h;
  __builtin_memcpy(&h, &u, 2);
  return (float)h;
}

#define GLOAD16(GP, LP) __builtin_amdgcn_global_load_lds( \
    (const __attribute__((address_space(1))) void*)(GP),  \
    (__attribute__((address_space(3))) void*)(LP), 16, 0, 0)

// ======== MFMA GEMM (f16 in, f32 acc): C = alpha * A(MxK) @ B(NxK)^T (+bias) ========
template<int BM, int BN, int OUT_F16, int ACT>
__global__ __launch_bounds__(256) void gemm_ht(
    const _Float16* __restrict__ A, long saz, int lda,
    const _Float16* __restrict__ B, long sbz, int ldb,
    void* __restrict__ Cv, long scz, int ldc,
    int K, float alpha, const float* __restrict__ bias)
{
  constexpr int FM = BM / 32, FN = BN / 32;
  __shared__ __align__(16) _Float16 Asl[BM * 32];
  __shared__ __align__(16) _Float16 Bsl[BN * 32];
  const int t = threadIdx.x;
  const int wid = t >> 6, lane = t & 63;
  const int wr = wid >> 1, wc = wid & 1;
  const int lr = lane & 15, kg = lane >> 4;
  A += (long)blockIdx.z * saz;
  B += (long)blockIdx.z * sbz;
  const long row0 = (long)blockIdx.y * BM;
  const long col0 = (long)blockIdx.x * BN;

  f32x4 acc[FM][FN];
  #pragma unroll
  for (int i = 0; i < FM; i++)
    #pragma unroll
    for (int j = 0; j < FN; j++)
      acc[i][j] = (f32x4){0.f, 0.f, 0.f, 0.f};

  const int arow_t = t >> 2, acol_t = (t & 3) * 8;

  for (int k0 = 0; k0 < K; k0 += 32){
    #pragma unroll
    for (int r = 0; r < BM / 64; r++){
      const _Float16* gp = A + (row0 + r*64 + arow_t) * (long)lda + k0 + acol_t;
      GLOAD16(gp, (char*)Asl + r*4096 + wid*1024);
    }
    #pragma unroll
    for (int r = 0; r < BN / 64; r++){
      const _Float16* gp = B + (col0 + r*64 + arow_t) * (long)ldb + k0 + acol_t;
      GLOAD16(gp, (char*)Bsl + r*4096 + wid*1024);
    }
    __syncthreads();
    half8 af[FM], bfv[FN];
    #pragma unroll
    for (int i = 0; i < FM; i++)
      af[i] = *(const half8*)((const char*)Asl + (wr*(BM/2) + i*16 + lr)*64 + kg*16);
    #pragma unroll
    for (int j = 0; j < FN; j++)
      bfv[j] = *(const half8*)((const char*)Bsl + (wc*(BN/2) + j*16 + lr)*64 + kg*16);
    #pragma unroll
    for (int i = 0; i < FM; i++)
      #pragma unroll
      for (int j = 0; j < FN; j++)
        acc[i][j] = __builtin_amdgcn_mfma_f32_16x16x32_f16(af[i], bfv[j], acc[i][j], 0, 0, 0);
    __syncthreads();
  }

  _Float16* Ch = (_Float16*)Cv + (long)blockIdx.z * scz;
  float*    Cf = (float*)Cv    + (long)blockIdx.z * scz;
  #pragma unroll
  for (int i = 0; i < FM; i++){
    #pragma unroll
    for (int j = 0; j < FN; j++){
      #pragma unroll
      for (int q = 0; q < 4; q++){
        long rr = row0 + wr*(BM/2) + i*16 + kg*4 + q;
        long cc = col0 + wc*(BN/2) + j*16 + lr;
        float val = acc[i][j][q] * alpha;
        if (bias) val += bias[cc];
        if constexpr (ACT) val = 0.5f * val * (1.0f + erff(val * 0.70710678118654752f));
        if constexpr (OUT_F16) Ch[rr*(long)ldc + cc] = (_Float16)val;
        else                   Cf[rr*(long)ldc + cc] = val;
      }
    }
  }
}

// ======== PV GEMM with fused exp/mask on A: Ph = exp(A - m)[*mask] @ B^T ========
// A = f16 scores [2][4096][4096]; mlthr[row] = {m, l, thr, 0}; f16 partials.
// z = batch*nsplit + split; partial z at Ph + z*4096*256. grid (1, 64, z).
template<int BM, int BN, int SPARSE>
__global__ __launch_bounds__(256) void gemm_pv_exp(
    const _Float16* __restrict__ A, long saz, int lda,
    const _Float16* __restrict__ B, long sbz, int ldb,
    const float4* __restrict__ mlthr,
    _Float16* __restrict__ Ph, int nsplit, int Ksplit)
{
  constexpr int FM = BM / 32, FN = BN / 32;
  __shared__ __align__(16) _Float16 Asl[BM * 32];
  __shared__ __align__(16) _Float16 Bsl[BN * 32];
  const int t = threadIdx.x;
  const int wid = t >> 6, lane = t & 63;
  const int wr = wid >> 1, wc = wid & 1;
  const int lr = lane & 15, kg = lane >> 4;
  const int z = blockIdx.z, batch = z / nsplit, split = z % nsplit;
  A += (long)batch * saz;
  B += (long)batch * sbz;
  _Float16* Pz = Ph + (size_t)z * (4096 * 256);
  const long row0 = (long)blockIdx.y * BM;
  const int Kbase = split * Ksplit;

  // per-thread A row is constant across K
  const long arow = row0 + (t >> 2);
  const float4 mt = mlthr[(long)batch*4096 + arow];
  const float m = mt.x, thr = mt.z;
  const _Float16* Ap = A + arow * (long)lda + Kbase + (t & 3) * 8;

  f32x4 acc[FM][FN];
  #pragma unroll
  for (int i = 0; i < FM; i++)
    #pragma unroll
    for (int j = 0; j < FN; j++)
      acc[i][j] = (f32x4){0.f, 0.f, 0.f, 0.f};

  const int arow_t = t >> 2, acol_t = (t & 3) * 8;

  for (int k0 = 0; k0 < Ksplit; k0 += 32){
    // B staging via async DMA (issue first)
    #pragma unroll
    for (int r = 0; r < BN / 64; r++){
      const _Float16* gp = B + (r*64 + arow_t) * (long)ldb + Kbase + k0 + acol_t;
      GLOAD16(gp, (char*)Bsl + r*4096 + wid*1024);
    }
    // A staging: reg load + exp(+mask) + LDS write at the SAME address layout
    {
      half8 ld = *(const half8*)(Ap + k0);
      half8 st;
      #pragma unroll
      for (int e = 0; e < 8; e++){
        float v = (float)ld[e];
        float ev;
        if constexpr (SPARSE) ev = (v >= thr) ? __expf(v - m) : 0.f;
        else                  ev = __expf(v - m);
        st[e] = (_Float16)ev;
      }
      *(half8*)((char*)Asl + t*16) = st;
    }
    __syncthreads();
    half8 af[FM], bfv[FN];
    #pragma unroll
    for (int i = 0; i < FM; i++)
      af[i] = *(const half8*)((const char*)Asl + (wr*(BM/2) + i*16 + lr)*64 + kg*16);
    #pragma unroll
    for (int j = 0; j < FN; j++)
      bfv[j] = *(const half8*)((const char*)Bsl + (wc*(BN/2) + j*16 + lr)*64 + kg*16);
    #pragma unroll
    for (int i = 0; i < FM; i++)
      #pragma unroll
      for (int j = 0; j < FN; j++)
        acc[i][j] = __builtin_amdgcn_mfma_f32_16x16x32_f16(af[i], bfv[j], acc[i][j], 0, 0, 0);
    __syncthreads();
  }

  #pragma unroll
  for (int i = 0; i < FM; i++)
    #pragma unroll
    for (int j = 0; j < FN; j++)
      #pragma unroll
      for (int q = 0; q < 4; q++){
        long rr = row0 + wr*(BM/2) + i*16 + kg*4 + q;
        long cc = wc*(BN/2) + j*16 + lr;
        Pz[rr*256 + cc] = (_Float16)acc[i][j][q];
      }
}

// ======== sum 4 f16 partials, divide by l -> f16 comb at column offset ========
__global__ __launch_bounds__(256) void reduce4h(const _Float16* __restrict__ Ph,
                                                const float4* __restrict__ mlthr,
                                                _Float16* __restrict__ dst, int coff, int nq){
  int i = blockIdx.x * 256 + threadIdx.x;
  if (i >= nq) return;
  int b = i >> 18;
  int r = i & 262143;
  int row = r >> 6, col4 = r & 63;
  float sx = 0.f, sy = 0.f, sz = 0.f, sw = 0.f;
  #pragma unroll
  for (int sp = 0; sp < 4; sp++){
    half4v p = *(const half4v*)(Ph + (((size_t)(b*4 + sp)*4096 + row)*256 + col4*4));
    sx += (float)p[0]; sy += (float)p[1]; sz += (float)p[2]; sw += (float)p[3];
  }
  const float inv = 1.0f / mlthr[(long)b*4096 + row].y;
  half4v o;
  o[0] = (_Float16)(sx*inv); o[1] = (_Float16)(sy*inv);
  o[2] = (_Float16)(sz*inv); o[3] = (_Float16)(sw*inv);
  *(half4v*)(dst + ((size_t)b*4096 + row)*1024 + coff + col4*4) = o;
}

// ======== cast f32 -> f16 (8 elems/thread) ========
__global__ __launch_bounds__(256) void cast_xh(const float* __restrict__ in,
                                               _Float16* __restrict__ out, int n8){
  int i = blockIdx.x * 256 + threadIdx.x;
  const int stride = gridDim.x * 256;
  for (; i < n8; i += stride){
    float4 a = ((const float4*)in)[2*i];
    float4 b = ((const float4*)in)[2*i + 1];
    half8 o;
    o[0]=(_Float16)a.x; o[1]=(_Float16)a.y; o[2]=(_Float16)a.z; o[3]=(_Float16)a.w;
    o[4]=(_Float16)b.x; o[5]=(_Float16)b.y; o[6]=(_Float16)b.z; o[7]=(_Float16)b.w;
    *(half8*)(out + (size_t)i*8) = o;
  }
}

// ======== transpose+cast weight: in (R x C) f32 -> out (C x R) f16 ========
__global__ __launch_bounds__(256) void transpose_cast_w(const float* __restrict__ in, int R, int C,
                                                        _Float16* __restrict__ out){
  __shared__ float tile[32][33];
  const int c0 = blockIdx.x * 32, r0 = blockIdx.y * 32;
  const int tx = threadIdx.x & 31, ty = threadIdx.x >> 5;
  #pragma unroll
  for (int i = 0; i < 32; i += 8)
    tile[ty+i][tx] = in[(size_t)(r0+ty+i)*C + c0+tx];
  __syncthreads();
  #pragma unroll
  for (int i = 0; i < 32; i += 8)
    out[(size_t)(c0+ty+i)*R + r0+tx] = (_Float16)tile[tx][ty+i];
}

// ======== f16 transpose: in (R x C, ld_in) -> out (C x R, ld_out), z-batched ========
__global__ __launch_bounds__(256) void transpose_h(
    const _Float16* __restrict__ in, long in_z, int ld_in,
    _Float16* __restrict__ out, long out_z, int ld_out)
{
  __shared__ _Float16 tile[32][34];
  const _Float16* ip = in + (long)blockIdx.z * in_z;
  _Float16* op = out + (long)blockIdx.z * out_z;
  const int c0 = blockIdx.x * 32, r0 = blockIdx.y * 32;
  const int tx = threadIdx.x & 31, ty = threadIdx.x >> 5;
  #pragma unroll
  for (int i = 0; i < 32; i += 8)
    tile[ty+i][tx] = ip[(long)(r0+ty+i)*ld_in + c0+tx];
  __syncthreads();
  #pragma unroll
  for (int i = 0; i < 32; i += 8)
    op[(long)(c0+ty+i)*ld_out + r0+tx] = tile[tx][ty+i];
}

// ======== rowstat (local): m = rowmax, l = sum exp(v-m); read-only ========
__global__ __launch_bounds__(256) void rowstat_local(const _Float16* __restrict__ sc,
                                                     float4* __restrict__ mlthr){
  __shared__ float red[4], red2[4];
  const int t = threadIdx.x, lane = t & 63, wid = t >> 6;
  const _Float16* p = sc + (size_t)blockIdx.x * 4096;
  half8 a = ((const half8*)p)[t*2];
  half8 b = ((const half8*)p)[t*2 + 1];
  float v[16];
  #pragma unroll
  for (int e = 0; e < 8; e++){ v[e] = (float)a[e]; v[8+e] = (float)b[e]; }
  float m = v[0];
  #pragma unroll
  for (int e = 1; e < 16; e++) m = fmaxf(m, v[e]);
  m = wred_max(m);
  if (lane == 0) red[wid] = m;
  __syncthreads();
  m = fmaxf(fmaxf(red[0], red[1]), fmaxf(red[2], red[3]));
  float s = 0.f;
  #pragma unroll
  for (int e = 0; e < 16; e++) s += __expf(v[e] - m);
  s = wred_sum(s);
  if (lane == 0) red2[wid] = s;
  __syncthreads();
  if (t == 0){
    s = red2[0] + red2[1] + red2[2] + red2[3];
    mlthr[blockIdx.x] = make_float4(m, s, -3.0e38f, 0.f);
  }
}

// ======== rowstat (sparse): exact top-k threshold (2x8-bit radix on u16 keys) ========
// outputs {m, l_masked, thr_value}; no score write-back.
__global__ __launch_bounds__(256) void rowstat_sparse(const _Float16* __restrict__ sc,
                                                      float4* __restrict__ mlthr, int ksel){
  __shared__ unsigned hist4[4][256];
  __shared__ unsigned hrev[256];
  __shared__ unsigned suf[257];
  __shared__ unsigned wtot[4];
  __shared__ int selb;
  __shared__ float red[4], red2[4];
  const int t = threadIdx.x, lane = t & 63, wid = t >> 6;
  const _Float16* p = sc + (size_t)blockIdx.x * 4096;
  half8 a = ((const half8*)p)[t*2];
  half8 b = ((const half8*)p)[t*2 + 1];
  float v[16]; unsigned kk[16];
  #pragma unroll
  for (int e = 0; e < 8; e++){
    unsigned short u0 = h2u(a[e]);
    unsigned short u1 = h2u(b[e]);
    kk[e]   = (u0 & 0x8000u) ? (unsigned)(unsigned short)~u0 : (unsigned)(u0 | 0x8000u);
    kk[8+e] = (u1 & 0x8000u) ? (unsigned)(unsigned short)~u1 : (unsigned)(u1 | 0x8000u);
    v[e] = (float)a[e]; v[8+e] = (float)b[e];
  }
  float m = v[0];
  #pragma unroll
  for (int e = 1; e < 16; e++) m = fmaxf(m, v[e]);
  m = wred_max(m);
  if (lane == 0) red[wid] = m;
  __syncthreads();
  m = fmaxf(fmaxf(red[0], red[1]), fmaxf(red[2], red[3]));

  // ---- pass 1: high byte ----
  ((uint4*)hist4)[t] = (uint4){0u,0u,0u,0u};
  __syncthreads();
  #pragma unroll
  for (int e = 0; e < 16; e++) atomicAdd(&hist4[wid][kk[e] >> 8], 1u);
  __syncthreads();
  hrev[t] = hist4[0][t] + hist4[1][t] + hist4[2][t] + hist4[3][t];
  __syncthreads();
  unsigned x = hrev[255 - t];
  #pragma unroll
  for (int o = 1; o < 64; o <<= 1){
    unsigned y = __shfl_up(x, o);
    if (lane >= o) x += y;
  }
  if (lane == 63) wtot[wid] = x;
  __syncthreads();
  #pragma unroll
  for (int w = 0; w < 4; w++) if (w < wid) x += wtot[w];
  suf[255 - t] = x;
  if (t == 0) suf[256] = 0u;
  __syncthreads();
  const unsigned ku = (unsigned)ksel;
  if (suf[t] >= ku && suf[t+1] < ku) selb = t;
  __syncthreads();
  const int b1 = selb;
  const unsigned rem = ku - suf[b1+1];
  __syncthreads();

  // ---- pass 2: low byte among high==b1 ----
  ((uint4*)hist4)[t] = (uint4){0u,0u,0u,0u};
  __syncthreads();
  #pragma unroll
  for (int e = 0; e < 16; e++)
    if ((int)(kk[e] >> 8) == b1) atomicAdd(&hist4[wid][kk[e] & 255u], 1u);
  __syncthreads();
  hrev[t] = hist4[0][t] + hist4[1][t] + hist4[2][t] + hist4[3][t];
  __syncthreads();
  x = hrev[255 - t];
  #pragma unroll
  for (int o = 1; o < 64; o <<= 1){
    unsigned y = __shfl_up(x, o);
    if (lane >= o) x += y;
  }
  if (lane == 63) wtot[wid] = x;
  __syncthreads();
  #pragma unroll
  for (int w = 0; w < 4; w++) if (w < wid) x += wtot[w];
  suf[255 - t] = x;
  if (t == 0) suf[256] = 0u;
  __syncthreads();
  if (suf[t] >= rem && suf[t+1] < rem) selb = t;
  __syncthreads();
  const unsigned Tkey = ((unsigned)b1 << 8) | (unsigned)selb;
  // threshold VALUE (matches reference's float >= compare)
  const unsigned short tu = (Tkey & 0x8000u) ? (unsigned short)(Tkey & 0x7fffu)
                                             : (unsigned short)~Tkey;
  const float thr = u2hf(tu);

  float s = 0.f;
  #pragma unroll
  for (int e = 0; e < 16; e++)
    s += (v[e] >= thr) ? __expf(v[e] - m) : 0.f;
  s = wred_sum(s);
  if (lane == 0) red2[wid] = s;
  __syncthreads();
  if (t == 0){
    s = red2[0] + red2[1] + red2[2] + red2[3];
    mlthr[blockIdx.x] = make_float4(m, s, thr, 0.f);
  }
}

// ======== memory-head softmax over 64 scores: one wave per row ========
__global__ __launch_bounds__(256) void msoftmax64(const float* __restrict__ mscore,
                                                  _Float16* __restrict__ mprob){
  const int t = threadIdx.x, lane = t & 63, wid = t >> 6;
  const size_t row = (size_t)blockIdx.x * 4 + wid;
  float v = mscore[row*64 + lane];
  float m = wred_max(v);
  float e = expf(v - m);
  float s = wred_sum(e);
  mprob[row*64 + lane] = (_Float16)(e / s);
}

extern "C" void kernel_launch(void* const* d_in, const int* in_sizes, int n_in,
                              void* d_out, int out_size, void* d_ws, size_t ws_size,
                              hipStream_t stream)
{
  const float* x             = (const float*)d_in[0];
  const float* local_qkv_w   = (const float*)d_in[1];
  const float* sparse_qkv_w  = (const float*)d_in[2];
  const float* memory_bank   = (const float*)d_in[3];
  const float* memory_proj_w = (const float*)d_in[4];
  const float* mem_out_w     = (const float*)d_in[5];
  const float* mem_out_b     = (const float*)d_in[6];
  const float* pred_in_w     = (const float*)d_in[7];
  const float* pred_in_b     = (const float*)d_in[8];
  const float* pred1_w       = (const float*)d_in[9];
  const float* pred1_b       = (const float*)d_in[10];
  const float* pred2_w       = (const float*)d_in[11];
  const float* pred2_b       = (const float*)d_in[12];
  const float* warboss_w     = (const float*)d_in[13];
  const float* warboss_b     = (const float*)d_in[14];
  float* out = (float*)d_out;
  _Float16* Ph = (_Float16*)d_out;   // f16 PV partials [8][4096][256] = 16.8MB < 33.5MB

  char* wsb = (char*)d_ws;
  _Float16*  scores_h = (_Float16*)wsb;                // [2][4096][4096] f16 (67MB)
  _Float16*  x_h      = (_Float16*)wsb;
  _Float16*  mem_cat  = (_Float16*)(wsb + 16777216);
  _Float16*  h_in     = (_Float16*)(wsb + 25165824);
  _Float16*  h1       = (_Float16*)(wsb + 29360128);
  float*     mscore   = (float*)(wsb + 37748736);
  _Float16*  mprob    = (_Float16*)(wsb + 39845888);
  _Float16*  qkv_l    = (_Float16*)(wsb + 67108864);   // [8192][768]
  _Float16*  qkv_s    = (_Float16*)(wsb + 79691776);   // [8192][768]
  _Float16*  Vt       = (_Float16*)(wsb + 92274688);   // [2][256][4096]
  _Float16*  comb     = (_Float16*)(wsb + 96468992);   // [8192][1024]
  _Float16*  lqkvT    = (_Float16*)(wsb + 113246208);  // [768][1024]
  _Float16*  sqkvT    = lqkvT  + 786432;
  _Float16*  mprojT   = sqkvT  + 786432;               // [256][1024]
  _Float16*  moutT    = mprojT + 262144;               // [256][512]
  _Float16*  pinT     = moutT  + 131072;               // [256][1024]
  _Float16*  p1T      = pinT   + 262144;               // [512][256]
  _Float16*  p2T      = p1T    + 131072;               // [256][512]
  _Float16*  wbT      = p2T    + 131072;               // [1024][1024]
  _Float16*  bank_h   = wbT    + 1048576;              // [64][256]
  _Float16*  bankT_h  = bank_h + 16384;                // [256][64]
  float4*    mlthr    = (float4*)(bankT_h + 16384);    // [2][4096] {m,l,thr}

  const dim3 blk(256);
  const float scale = 0.0625f;
  const long QZ  = (long)4096 * 768;
  const long VZ  = (long)256 * 4096;
  const long SZH = (long)4096 * 4096;

  // ---- casts / weight transposes ----
  cast_xh<<<dim3(2048), blk, 0, stream>>>(x, x_h, 1048576);
  cast_xh<<<dim3(8), blk, 0, stream>>>(memory_bank, bank_h, 2048);
  transpose_cast_w<<<dim3(24,32), blk, 0, stream>>>(local_qkv_w,  1024,  768, lqkvT);
  transpose_cast_w<<<dim3(24,32), blk, 0, stream>>>(sparse_qkv_w, 1024,  768, sqkvT);
  transpose_cast_w<<<dim3( 8,32), blk, 0, stream>>>(memory_proj_w,1024,  256, mprojT);
  transpose_cast_w<<<dim3( 8,16), blk, 0, stream>>>(mem_out_w,     512,  256, moutT);
  transpose_cast_w<<<dim3( 8,32), blk, 0, stream>>>(pred_in_w,    1024,  256, pinT);
  transpose_cast_w<<<dim3(16, 8), blk, 0, stream>>>(pred1_w,       256,  512, p1T);
  transpose_cast_w<<<dim3( 8,16), blk, 0, stream>>>(pred2_w,       512,  256, p2T);
  transpose_cast_w<<<dim3(32,32), blk, 0, stream>>>(warboss_w,    1024, 1024, wbT);
  transpose_cast_w<<<dim3( 8, 2), blk, 0, stream>>>(memory_bank,    64,  256, bankT_h);

  // ---- QKV projections (merged z=2: local / sparse) ----
  gemm_ht<128,128,1,0><<<dim3(6,64,2), blk, 0, stream>>>(x_h,0,1024, lqkvT,786432,1024,
                                                         qkv_l,6291456,768, 1024, 1.f, nullptr);

  // ---- memory head (GEMM chain) -> comb[:, 512:768] ----
  gemm_ht<64,64,1,0><<<dim3(4,128), blk, 0, stream>>>(x_h,0,1024, mprojT,0,1024, mem_cat,0,512, 1024, 1.f, nullptr);
  gemm_ht<64,64,0,0><<<dim3(1,128), blk, 0, stream>>>(mem_cat,0,512, bank_h,0,256, (void*)mscore,0,64, 256, 1.f, nullptr);
  msoftmax64<<<dim3(2048), blk, 0, stream>>>(mscore, mprob);
  gemm_ht<64,64,1,0><<<dim3(4,128), blk, 0, stream>>>(mprob,0,64, bankT_h,0,64, mem_cat+256,0,512, 64, 1.f, nullptr);
  gemm_ht<64,64,1,0><<<dim3(4,128), blk, 0, stream>>>(mem_cat,0,512, moutT,0,512, comb+512,0,1024, 512, 1.f, mem_out_b);

  // ---- prediction head -> comb[:, 768:1024] ----
  gemm_ht<64,64,1,0><<<dim3(4,128), blk, 0, stream>>>(x_h,0,1024, pinT,0,1024, h_in,0,256, 1024, 1.f, pred_in_b);
  gemm_ht<64,128,1,1><<<dim3(4,128), blk, 0, stream>>>(h_in,0,256, p1T,0,256, h1,0,512, 256, 1.f, pred1_b);
  gemm_ht<64,64,1,0><<<dim3(4,128), blk, 0, stream>>>(h1,0,512, p2T,0,512, comb+768,0,1024, 512, 1.f, pred2_b);

  // ---- local (full) attention -> comb[:, 0:256] ----
  transpose_h<<<dim3(8,128,2), blk, 0, stream>>>(qkv_l+512, QZ, 768, Vt, VZ, 4096);
  gemm_ht<128,128,1,0><<<dim3(32,32,2), blk, 0, stream>>>(qkv_l,QZ,768, qkv_l+256,QZ,768,
                                                          (void*)scores_h,SZH,4096, 256, scale, nullptr);
  rowstat_local<<<dim3(8192), blk, 0, stream>>>(scores_h, mlthr);
  gemm_pv_exp<64,256,0><<<dim3(1,64,8), blk, 0, stream>>>(scores_h,SZH,4096, Vt,VZ,4096, mlthr, Ph, 4, 1024);
  reduce4h<<<dim3(2048), blk, 0, stream>>>(Ph, mlthr, comb, 0, 524288);

  // ---- sparse (top-k) attention -> comb[:, 256:512] ----
  transpose_h<<<dim3(8,128,2), blk, 0, stream>>>(qkv_s+512, QZ, 768, Vt, VZ, 4096);
  gemm_ht<128,128,1,0><<<dim3(32,32,2), blk, 0, stream>>>(qkv_s,QZ,768, qkv_s+256,QZ,768,
                                                          (void*)scores_h,SZH,4096, 256, scale, nullptr);
  rowstat_sparse<<<dim3(8192), blk, 0, stream>>>(scores_h, mlthr, 409);
  gemm_pv_exp<64,256,1><<<dim3(1,64,8), blk, 0, stream>>>(scores_h,SZH,4096, Vt,VZ,4096, mlthr, Ph, 4, 1024);
  reduce4h<<<dim3(2048), blk, 0, stream>>>(Ph, mlthr, comb, 256, 524288);

  // ---- output projection (f32 out; overwrites the Ph scratch region) ----
  gemm_ht<128,128,0,0><<<dim3(8,64), blk, 0, stream>>>(comb,0,1024, wbT,0,1024, (void*)out,0,1024, 1024, 1.f, warboss_b);
}

// Round 13
// 390.642 us; speedup vs baseline: 1.8359x; 1.0320x over previous
//
#include <hip/hip_runtime.h>
#include <hip/hip_bf16.h>

typedef __attribute__((ext_vector_type(8))) _Float16 half8;
typedef __attribute__((ext_vector_type(4))) _Float16 half4v;
typedef __attribute__((ext_vector_type(4))) float f32x4;

__device__ __forceinline__ float wred_max(float v){
  #pragma unroll
  for (int o = 32; o; o >>= 1) v = fmaxf(v, __shfl_xor(v, o));
  return v;
}
__device__ __forceinline__ float wred_sum(float v){
  #pragma unroll
  for (int o = 32; o; o >>= 1) v += __shfl_xor(v, o);
  return v;
}
__device__ __forceinline__ unsigned short h2u(_Float16 h){
  unsigned short u;
  __builtin_memcpy(&u, &h, 2);
  return u;
}
__device__ __forceinline__ float u2hf(unsigned short u){
  _Float16 h;
  __builtin_memcpy(&h, &u, 2);
  return (float)h;
}

#define GLOAD16(GP, LP) __builtin_amdgcn_global_load_lds( \
    (const __attribute__((address_space(1))) void*)(GP),  \
    (__attribute__((address_space(3))) void*)(LP), 16, 0, 0)

// ======== MFMA GEMM, 2-phase double-buffered: C = alpha * A @ B^T (+bias) ========
template<int BM, int BN, int OUT_F16, int ACT>
__global__ __launch_bounds__(256) void gemm_ht(
    const _Float16* __restrict__ A, long saz, int lda,
    const _Float16* __restrict__ B, long sbz, int ldb,
    void* __restrict__ Cv, long scz, int ldc,
    int K, float alpha, const float* __restrict__ bias)
{
  constexpr int FM = BM / 32, FN = BN / 32;
  __shared__ __align__(16) _Float16 Asl[2][BM * 32];
  __shared__ __align__(16) _Float16 Bsl[2][BN * 32];
  const int t = threadIdx.x;
  const int wid = t >> 6, lane = t & 63;
  const int wr = wid >> 1, wc = wid & 1;
  const int lr = lane & 15, kg = lane >> 4;
  A += (long)blockIdx.z * saz;
  B += (long)blockIdx.z * sbz;
  const long row0 = (long)blockIdx.y * BM;
  const long col0 = (long)blockIdx.x * BN;

  const int arow_t = t >> 2, acol_t = (t & 3) * 8;

  auto stage = [&](int buf, int k0){
    #pragma unroll
    for (int r = 0; r < BM / 64; r++){
      const _Float16* gp = A + (row0 + r*64 + arow_t) * (long)lda + k0 + acol_t;
      GLOAD16(gp, (char*)Asl[buf] + r*4096 + wid*1024);
    }
    #pragma unroll
    for (int r = 0; r < BN / 64; r++){
      const _Float16* gp = B + (col0 + r*64 + arow_t) * (long)ldb + k0 + acol_t;
      GLOAD16(gp, (char*)Bsl[buf] + r*4096 + wid*1024);
    }
  };

  f32x4 acc[FM][FN];
  #pragma unroll
  for (int i = 0; i < FM; i++)
    #pragma unroll
    for (int j = 0; j < FN; j++)
      acc[i][j] = (f32x4){0.f, 0.f, 0.f, 0.f};

  stage(0, 0);
  __syncthreads();
  int cur = 0;
  for (int k0 = 0; k0 < K; k0 += 32){
    if (k0 + 32 < K) stage(cur ^ 1, k0 + 32);   // prefetch next tile (async)
    half8 af[FM], bfv[FN];
    #pragma unroll
    for (int i = 0; i < FM; i++)
      af[i] = *(const half8*)((const char*)Asl[cur] + (wr*(BM/2) + i*16 + lr)*64 + kg*16);
    #pragma unroll
    for (int j = 0; j < FN; j++)
      bfv[j] = *(const half8*)((const char*)Bsl[cur] + (wc*(BN/2) + j*16 + lr)*64 + kg*16);
    #pragma unroll
    for (int i = 0; i < FM; i++)
      #pragma unroll
      for (int j = 0; j < FN; j++)
        acc[i][j] = __builtin_amdgcn_mfma_f32_16x16x32_f16(af[i], bfv[j], acc[i][j], 0, 0, 0);
    __syncthreads();   // drains prefetch (vmcnt) + ds reads; one barrier per step
    cur ^= 1;
  }

  _Float16* Ch = (_Float16*)Cv + (long)blockIdx.z * scz;
  float*    Cf = (float*)Cv    + (long)blockIdx.z * scz;
  #pragma unroll
  for (int i = 0; i < FM; i++){
    #pragma unroll
    for (int j = 0; j < FN; j++){
      #pragma unroll
      for (int q = 0; q < 4; q++){
        long rr = row0 + wr*(BM/2) + i*16 + kg*4 + q;
        long cc = col0 + wc*(BN/2) + j*16 + lr;
        float val = acc[i][j][q] * alpha;
        if (bias) val += bias[cc];
        if constexpr (ACT) val = 0.5f * val * (1.0f + erff(val * 0.70710678118654752f));
        if constexpr (OUT_F16) Ch[rr*(long)ldc + cc] = (_Float16)val;
        else                   Cf[rr*(long)ldc + cc] = val;
      }
    }
  }
}

// ======== PV GEMM, 2-phase dbuf, fused exp/mask on A (reg-staged, write-late) ========
// A = f16 scores; mlthr[row] = {m, l, thr}; f16 partials to Ph.
template<int BM, int BN, int SPARSE>
__global__ __launch_bounds__(256) void gemm_pv_exp(
    const _Float16* __restrict__ A, long saz, int lda,
    const _Float16* __restrict__ B, long sbz, int ldb,
    const float4* __restrict__ mlthr,
    _Float16* __restrict__ Ph, int nsplit, int Ksplit)
{
  constexpr int FM = BM / 32, FN = BN / 32;
  __shared__ __align__(16) _Float16 Asl[2][BM * 32];
  __shared__ __align__(16) _Float16 Bsl[2][BN * 32];
  const int t = threadIdx.x;
  const int wid = t >> 6, lane = t & 63;
  const int wr = wid >> 1, wc = wid & 1;
  const int lr = lane & 15, kg = lane >> 4;
  const int z = blockIdx.z, batch = z / nsplit, split = z % nsplit;
  A += (long)batch * saz;
  B += (long)batch * sbz;
  _Float16* Pz = Ph + (size_t)z * (4096 * 256);
  const long row0 = (long)blockIdx.y * BM;
  const int Kbase = split * Ksplit;

  const long arow = row0 + (t >> 2);
  const float4 mt = mlthr[(long)batch*4096 + arow];
  const float m = mt.x, thr = mt.z;
  const _Float16* Ap = A + arow * (long)lda + Kbase + (t & 3) * 8;

  const int arow_t = t >> 2, acol_t = (t & 3) * 8;

  auto stageB = [&](int buf, int k0){
    #pragma unroll
    for (int r = 0; r < BN / 64; r++){
      const _Float16* gp = B + (r*64 + arow_t) * (long)ldb + Kbase + k0 + acol_t;
      GLOAD16(gp, (char*)Bsl[buf] + r*4096 + wid*1024);
    }
  };
  auto expw = [&](int buf, half8 ld){
    half8 st;
    #pragma unroll
    for (int e = 0; e < 8; e++){
      float v = (float)ld[e];
      float ev;
      if constexpr (SPARSE) ev = (v >= thr) ? __expf(v - m) : 0.f;
      else                  ev = __expf(v - m);
      st[e] = (_Float16)ev;
    }
    *(half8*)((char*)Asl[buf] + t*16) = st;
  };

  f32x4 acc[FM][FN];
  #pragma unroll
  for (int i = 0; i < FM; i++)
    #pragma unroll
    for (int j = 0; j < FN; j++)
      acc[i][j] = (f32x4){0.f, 0.f, 0.f, 0.f};

  // prologue: tile 0
  stageB(0, 0);
  expw(0, *(const half8*)(Ap + 0));
  __syncthreads();
  int cur = 0;
  for (int k0 = 0; k0 < Ksplit; k0 += 32){
    const bool more = (k0 + 32 < Ksplit);
    half8 lda_next;
    if (more){
      stageB(cur ^ 1, k0 + 32);                 // async B prefetch
      lda_next = *(const half8*)(Ap + k0 + 32); // A reg prefetch (issue early)
    }
    half8 af[FM], bfv[FN];
    #pragma unroll
    for (int i = 0; i < FM; i++)
      af[i] = *(const half8*)((const char*)Asl[cur] + (wr*(BM/2) + i*16 + lr)*64 + kg*16);
    #pragma unroll
    for (int j = 0; j < FN; j++)
      bfv[j] = *(const half8*)((const char*)Bsl[cur] + (wc*(BN/2) + j*16 + lr)*64 + kg*16);
    #pragma unroll
    for (int i = 0; i < FM; i++)
      #pragma unroll
      for (int j = 0; j < FN; j++)
        acc[i][j] = __builtin_amdgcn_mfma_f32_16x16x32_f16(af[i], bfv[j], acc[i][j], 0, 0, 0);
    if (more) expw(cur ^ 1, lda_next);          // exp + LDS write (latency hidden)
    __syncthreads();
    cur ^= 1;
  }

  #pragma unroll
  for (int i = 0; i < FM; i++)
    #pragma unroll
    for (int j = 0; j < FN; j++)
      #pragma unroll
      for (int q = 0; q < 4; q++){
        long rr = row0 + wr*(BM/2) + i*16 + kg*4 + q;
        long cc = wc*(BN/2) + j*16 + lr;
        Pz[rr*256 + cc] = (_Float16)acc[i][j][q];
      }
}

// ======== sum 4 f16 partials, divide by l -> f16 comb at column offset ========
__global__ __launch_bounds__(256) void reduce4h(const _Float16* __restrict__ Ph,
                                                const float4* __restrict__ mlthr,
                                                _Float16* __restrict__ dst, int coff, int nq){
  int i = blockIdx.x * 256 + threadIdx.x;
  if (i >= nq) return;
  int b = i >> 18;
  int r = i & 262143;
  int row = r >> 6, col4 = r & 63;
  float sx = 0.f, sy = 0.f, sz = 0.f, sw = 0.f;
  #pragma unroll
  for (int sp = 0; sp < 4; sp++){
    half4v p = *(const half4v*)(Ph + (((size_t)(b*4 + sp)*4096 + row)*256 + col4*4));
    sx += (float)p[0]; sy += (float)p[1]; sz += (float)p[2]; sw += (float)p[3];
  }
  const float inv = 1.0f / mlthr[(long)b*4096 + row].y;
  half4v o;
  o[0] = (_Float16)(sx*inv); o[1] = (_Float16)(sy*inv);
  o[2] = (_Float16)(sz*inv); o[3] = (_Float16)(sw*inv);
  *(half4v*)(dst + ((size_t)b*4096 + row)*1024 + coff + col4*4) = o;
}

// ======== cast f32 -> f16 (8 elems/thread) ========
__global__ __launch_bounds__(256) void cast_xh(const float* __restrict__ in,
                                               _Float16* __restrict__ out, int n8){
  int i = blockIdx.x * 256 + threadIdx.x;
  const int stride = gridDim.x * 256;
  for (; i < n8; i += stride){
    float4 a = ((const float4*)in)[2*i];
    float4 b = ((const float4*)in)[2*i + 1];
    half8 o;
    o[0]=(_Float16)a.x; o[1]=(_Float16)a.y; o[2]=(_Float16)a.z; o[3]=(_Float16)a.w;
    o[4]=(_Float16)b.x; o[5]=(_Float16)b.y; o[6]=(_Float16)b.z; o[7]=(_Float16)b.w;
    *(half8*)(out + (size_t)i*8) = o;
  }
}

// ======== transpose+cast weight: in (R x C) f32 -> out (C x R) f16 ========
__global__ __launch_bounds__(256) void transpose_cast_w(const float* __restrict__ in, int R, int C,
                                                        _Float16* __restrict__ out){
  __shared__ float tile[32][33];
  const int c0 = blockIdx.x * 32, r0 = blockIdx.y * 32;
  const int tx = threadIdx.x & 31, ty = threadIdx.x >> 5;
  #pragma unroll
  for (int i = 0; i < 32; i += 8)
    tile[ty+i][tx] = in[(size_t)(r0+ty+i)*C + c0+tx];
  __syncthreads();
  #pragma unroll
  for (int i = 0; i < 32; i += 8)
    out[(size_t)(c0+ty+i)*R + r0+tx] = (_Float16)tile[tx][ty+i];
}

// ======== f16 transpose: in (R x C, ld_in) -> out (C x R, ld_out), z-batched ========
__global__ __launch_bounds__(256) void transpose_h(
    const _Float16* __restrict__ in, long in_z, int ld_in,
    _Float16* __restrict__ out, long out_z, int ld_out)
{
  __shared__ _Float16 tile[32][34];
  const _Float16* ip = in + (long)blockIdx.z * in_z;
  _Float16* op = out + (long)blockIdx.z * out_z;
  const int c0 = blockIdx.x * 32, r0 = blockIdx.y * 32;
  const int tx = threadIdx.x & 31, ty = threadIdx.x >> 5;
  #pragma unroll
  for (int i = 0; i < 32; i += 8)
    tile[ty+i][tx] = ip[(long)(r0+ty+i)*ld_in + c0+tx];
  __syncthreads();
  #pragma unroll
  for (int i = 0; i < 32; i += 8)
    op[(long)(c0+ty+i)*ld_out + r0+tx] = tile[tx][ty+i];
}

// ======== rowstat (local): m = rowmax, l = sum exp(v-m); read-only ========
__global__ __launch_bounds__(256) void rowstat_local(const _Float16* __restrict__ sc,
                                                     float4* __restrict__ mlthr){
  __shared__ float red[4], red2[4];
  const int t = threadIdx.x, lane = t & 63, wid = t >> 6;
  const _Float16* p = sc + (size_t)blockIdx.x * 4096;
  half8 a = ((const half8*)p)[t*2];
  half8 b = ((const half8*)p)[t*2 + 1];
  float v[16];
  #pragma unroll
  for (int e = 0; e < 8; e++){ v[e] = (float)a[e]; v[8+e] = (float)b[e]; }
  float m = v[0];
  #pragma unroll
  for (int e = 1; e < 16; e++) m = fmaxf(m, v[e]);
  m = wred_max(m);
  if (lane == 0) red[wid] = m;
  __syncthreads();
  m = fmaxf(fmaxf(red[0], red[1]), fmaxf(red[2], red[3]));
  float s = 0.f;
  #pragma unroll
  for (int e = 0; e < 16; e++) s += __expf(v[e] - m);
  s = wred_sum(s);
  if (lane == 0) red2[wid] = s;
  __syncthreads();
  if (t == 0){
    s = red2[0] + red2[1] + red2[2] + red2[3];
    mlthr[blockIdx.x] = make_float4(m, s, -3.0e38f, 0.f);
  }
}

// ======== rowstat (sparse): exact top-k threshold (2x8-bit radix on u16 keys) ========
__global__ __launch_bounds__(256) void rowstat_sparse(const _Float16* __restrict__ sc,
                                                      float4* __restrict__ mlthr, int ksel){
  __shared__ unsigned hist4[4][256];
  __shared__ unsigned hrev[256];
  __shared__ unsigned suf[257];
  __shared__ unsigned wtot[4];
  __shared__ int selb;
  __shared__ float red[4], red2[4];
  const int t = threadIdx.x, lane = t & 63, wid = t >> 6;
  const _Float16* p = sc + (size_t)blockIdx.x * 4096;
  half8 a = ((const half8*)p)[t*2];
  half8 b = ((const half8*)p)[t*2 + 1];
  float v[16]; unsigned kk[16];
  #pragma unroll
  for (int e = 0; e < 8; e++){
    unsigned short u0 = h2u(a[e]);
    unsigned short u1 = h2u(b[e]);
    kk[e]   = (u0 & 0x8000u) ? (unsigned)(unsigned short)~u0 : (unsigned)(u0 | 0x8000u);
    kk[8+e] = (u1 & 0x8000u) ? (unsigned)(unsigned short)~u1 : (unsigned)(u1 | 0x8000u);
    v[e] = (float)a[e]; v[8+e] = (float)b[e];
  }
  float m = v[0];
  #pragma unroll
  for (int e = 1; e < 16; e++) m = fmaxf(m, v[e]);
  m = wred_max(m);
  if (lane == 0) red[wid] = m;
  __syncthreads();
  m = fmaxf(fmaxf(red[0], red[1]), fmaxf(red[2], red[3]));

  // ---- pass 1: high byte ----
  ((uint4*)hist4)[t] = (uint4){0u,0u,0u,0u};
  __syncthreads();
  #pragma unroll
  for (int e = 0; e < 16; e++) atomicAdd(&hist4[wid][kk[e] >> 8], 1u);
  __syncthreads();
  hrev[t] = hist4[0][t] + hist4[1][t] + hist4[2][t] + hist4[3][t];
  __syncthreads();
  unsigned x = hrev[255 - t];
  #pragma unroll
  for (int o = 1; o < 64; o <<= 1){
    unsigned y = __shfl_up(x, o);
    if (lane >= o) x += y;
  }
  if (lane == 63) wtot[wid] = x;
  __syncthreads();
  #pragma unroll
  for (int w = 0; w < 4; w++) if (w < wid) x += wtot[w];
  suf[255 - t] = x;
  if (t == 0) suf[256] = 0u;
  __syncthreads();
  const unsigned ku = (unsigned)ksel;
  if (suf[t] >= ku && suf[t+1] < ku) selb = t;
  __syncthreads();
  const int b1 = selb;
  const unsigned rem = ku - suf[b1+1];
  __syncthreads();

  // ---- pass 2: low byte among high==b1 ----
  ((uint4*)hist4)[t] = (uint4){0u,0u,0u,0u};
  __syncthreads();
  #pragma unroll
  for (int e = 0; e < 16; e++)
    if ((int)(kk[e] >> 8) == b1) atomicAdd(&hist4[wid][kk[e] & 255u], 1u);
  __syncthreads();
  hrev[t] = hist4[0][t] + hist4[1][t] + hist4[2][t] + hist4[3][t];
  __syncthreads();
  x = hrev[255 - t];
  #pragma unroll
  for (int o = 1; o < 64; o <<= 1){
    unsigned y = __shfl_up(x, o);
    if (lane >= o) x += y;
  }
  if (lane == 63) wtot[wid] = x;
  __syncthreads();
  #pragma unroll
  for (int w = 0; w < 4; w++) if (w < wid) x += wtot[w];
  suf[255 - t] = x;
  if (t == 0) suf[256] = 0u;
  __syncthreads();
  if (suf[t] >= rem && suf[t+1] < rem) selb = t;
  __syncthreads();
  const unsigned Tkey = ((unsigned)b1 << 8) | (unsigned)selb;
  const unsigned short tu = (Tkey & 0x8000u) ? (unsigned short)(Tkey & 0x7fffu)
                                             : (unsigned short)~Tkey;
  const float thr = u2hf(tu);

  float s = 0.f;
  #pragma unroll
  for (int e = 0; e < 16; e++)
    s += (v[e] >= thr) ? __expf(v[e] - m) : 0.f;
  s = wred_sum(s);
  if (lane == 0) red2[wid] = s;
  __syncthreads();
  if (t == 0){
    s = red2[0] + red2[1] + red2[2] + red2[3];
    mlthr[blockIdx.x] = make_float4(m, s, thr, 0.f);
  }
}

// ======== memory-head softmax over 64 scores: one wave per row ========
__global__ __launch_bounds__(256) void msoftmax64(const float* __restrict__ mscore,
                                                  _Float16* __restrict__ mprob){
  const int t = threadIdx.x, lane = t & 63, wid = t >> 6;
  const size_t row = (size_t)blockIdx.x * 4 + wid;
  float v = mscore[row*64 + lane];
  float m = wred_max(v);
  float e = expf(v - m);
  float s = wred_sum(e);
  mprob[row*64 + lane] = (_Float16)(e / s);
}

extern "C" void kernel_launch(void* const* d_in, const int* in_sizes, int n_in,
                              void* d_out, int out_size, void* d_ws, size_t ws_size,
                              hipStream_t stream)
{
  const float* x             = (const float*)d_in[0];
  const float* local_qkv_w   = (const float*)d_in[1];
  const float* sparse_qkv_w  = (const float*)d_in[2];
  const float* memory_bank   = (const float*)d_in[3];
  const float* memory_proj_w = (const float*)d_in[4];
  const float* mem_out_w     = (const float*)d_in[5];
  const float* mem_out_b     = (const float*)d_in[6];
  const float* pred_in_w     = (const float*)d_in[7];
  const float* pred_in_b     = (const float*)d_in[8];
  const float* pred1_w       = (const float*)d_in[9];
  const float* pred1_b       = (const float*)d_in[10];
  const float* pred2_w       = (const float*)d_in[11];
  const float* pred2_b       = (const float*)d_in[12];
  const float* warboss_w     = (const float*)d_in[13];
  const float* warboss_b     = (const float*)d_in[14];
  float* out = (float*)d_out;
  _Float16* Ph = (_Float16*)d_out;   // f16 PV partials [8][4096][256] = 16.8MB

  char* wsb = (char*)d_ws;
  _Float16*  scores_h = (_Float16*)wsb;                // [2][4096][4096] f16 (67MB)
  _Float16*  x_h      = (_Float16*)wsb;
  _Float16*  mem_cat  = (_Float16*)(wsb + 16777216);
  _Float16*  h_in     = (_Float16*)(wsb + 25165824);
  _Float16*  h1       = (_Float16*)(wsb + 29360128);
  float*     mscore   = (float*)(wsb + 37748736);
  _Float16*  mprob    = (_Float16*)(wsb + 39845888);
  _Float16*  qkv_l    = (_Float16*)(wsb + 67108864);   // [8192][768]
  _Float16*  qkv_s    = (_Float16*)(wsb + 79691776);   // [8192][768]
  _Float16*  Vt       = (_Float16*)(wsb + 92274688);   // [2][256][4096]
  _Float16*  comb     = (_Float16*)(wsb + 96468992);   // [8192][1024]
  _Float16*  lqkvT    = (_Float16*)(wsb + 113246208);  // [768][1024]
  _Float16*  sqkvT    = lqkvT  + 786432;
  _Float16*  mprojT   = sqkvT  + 786432;               // [256][1024]
  _Float16*  moutT    = mprojT + 262144;               // [256][512]
  _Float16*  pinT     = moutT  + 131072;               // [256][1024]
  _Float16*  p1T      = pinT   + 262144;               // [512][256]
  _Float16*  p2T      = p1T    + 131072;               // [256][512]
  _Float16*  wbT      = p2T    + 131072;               // [1024][1024]
  _Float16*  bank_h   = wbT    + 1048576;              // [64][256]
  _Float16*  bankT_h  = bank_h + 16384;                // [256][64]
  float4*    mlthr    = (float4*)(bankT_h + 16384);    // [2][4096] {m,l,thr}

  const dim3 blk(256);
  const float scale = 0.0625f;
  const long QZ  = (long)4096 * 768;
  const long VZ  = (long)256 * 4096;
  const long SZH = (long)4096 * 4096;

  // ---- casts / weight transposes ----
  cast_xh<<<dim3(2048), blk, 0, stream>>>(x, x_h, 1048576);
  cast_xh<<<dim3(8), blk, 0, stream>>>(memory_bank, bank_h, 2048);
  transpose_cast_w<<<dim3(24,32), blk, 0, stream>>>(local_qkv_w,  1024,  768, lqkvT);
  transpose_cast_w<<<dim3(24,32), blk, 0, stream>>>(sparse_qkv_w, 1024,  768, sqkvT);
  transpose_cast_w<<<dim3( 8,32), blk, 0, stream>>>(memory_proj_w,1024,  256, mprojT);
  transpose_cast_w<<<dim3( 8,16), blk, 0, stream>>>(mem_out_w,     512,  256, moutT);
  transpose_cast_w<<<dim3( 8,32), blk, 0, stream>>>(pred_in_w,    1024,  256, pinT);
  transpose_cast_w<<<dim3(16, 8), blk, 0, stream>>>(pred1_w,       256,  512, p1T);
  transpose_cast_w<<<dim3( 8,16), blk, 0, stream>>>(pred2_w,       512,  256, p2T);
  transpose_cast_w<<<dim3(32,32), blk, 0, stream>>>(warboss_w,    1024, 1024, wbT);
  transpose_cast_w<<<dim3( 8, 2), blk, 0, stream>>>(memory_bank,    64,  256, bankT_h);

  // ---- QKV projections (merged z=2: local / sparse) ----
  gemm_ht<128,128,1,0><<<dim3(6,64,2), blk, 0, stream>>>(x_h,0,1024, lqkvT,786432,1024,
                                                         qkv_l,6291456,768, 1024, 1.f, nullptr);

  // ---- memory head (GEMM chain) -> comb[:, 512:768] ----
  gemm_ht<64,64,1,0><<<dim3(4,128), blk, 0, stream>>>(x_h,0,1024, mprojT,0,1024, mem_cat,0,512, 1024, 1.f, nullptr);
  gemm_ht<64,64,0,0><<<dim3(1,128), blk, 0, stream>>>(mem_cat,0,512, bank_h,0,256, (void*)mscore,0,64, 256, 1.f, nullptr);
  msoftmax64<<<dim3(2048), blk, 0, stream>>>(mscore, mprob);
  gemm_ht<64,64,1,0><<<dim3(4,128), blk, 0, stream>>>(mprob,0,64, bankT_h,0,64, mem_cat+256,0,512, 64, 1.f, nullptr);
  gemm_ht<64,64,1,0><<<dim3(4,128), blk, 0, stream>>>(mem_cat,0,512, moutT,0,512, comb+512,0,1024, 512, 1.f, mem_out_b);

  // ---- prediction head -> comb[:, 768:1024] ----
  gemm_ht<64,64,1,0><<<dim3(4,128), blk, 0, stream>>>(x_h,0,1024, pinT,0,1024, h_in,0,256, 1024, 1.f, pred_in_b);
  gemm_ht<64,128,1,1><<<dim3(4,128), blk, 0, stream>>>(h_in,0,256, p1T,0,256, h1,0,512, 256, 1.f, pred1_b);
  gemm_ht<64,64,1,0><<<dim3(4,128), blk, 0, stream>>>(h1,0,512, p2T,0,512, comb+768,0,1024, 512, 1.f, pred2_b);

  // ---- local (full) attention -> comb[:, 0:256] ----
  transpose_h<<<dim3(8,128,2), blk, 0, stream>>>(qkv_l+512, QZ, 768, Vt, VZ, 4096);
  gemm_ht<128,128,1,0><<<dim3(32,32,2), blk, 0, stream>>>(qkv_l,QZ,768, qkv_l+256,QZ,768,
                                                          (void*)scores_h,SZH,4096, 256, scale, nullptr);
  rowstat_local<<<dim3(8192), blk, 0, stream>>>(scores_h, mlthr);
  gemm_pv_exp<64,256,0><<<dim3(1,64,8), blk, 0, stream>>>(scores_h,SZH,4096, Vt,VZ,4096, mlthr, Ph, 4, 1024);
  reduce4h<<<dim3(2048), blk, 0, stream>>>(Ph, mlthr, comb, 0, 524288);

  // ---- sparse (top-k) attention -> comb[:, 256:512] ----
  transpose_h<<<dim3(8,128,2), blk, 0, stream>>>(qkv_s+512, QZ, 768, Vt, VZ, 4096);
  gemm_ht<128,128,1,0><<<dim3(32,32,2), blk, 0, stream>>>(qkv_s,QZ,768, qkv_s+256,QZ,768,
                                                          (void*)scores_h,SZH,4096, 256, scale, nullptr);
  rowstat_sparse<<<dim3(8192), blk, 0, stream>>>(scores_h, mlthr, 409);
  gemm_pv_exp<64,256,1><<<dim3(1,64,8), blk, 0, stream>>>(scores_h,SZH,4096, Vt,VZ,4096, mlthr, Ph, 4, 1024);
  reduce4h<<<dim3(2048), blk, 0, stream>>>(Ph, mlthr, comb, 256, 524288);

  // ---- output projection (f32 out; overwrites the Ph scratch region) ----
  gemm_ht<128,128,0,0><<<dim3(8,64), blk, 0, stream>>>(comb,0,1024, wbT,0,1024, (void*)out,0,1024, 1024, 1.f, warboss_b);
}